// Round 5
// baseline (375.588 us; speedup 1.0000x reference)
//
#include <hip/hip_runtime.h>

#define HW 65536
#define CB 64
#define NB 8

typedef __attribute__((ext_vector_type(4))) float f32x4;
typedef __attribute__((ext_vector_type(8))) short s16x8;

__device__ __forceinline__ float sigm(float v) { return 1.f / (1.f + __expf(-v)); }

__device__ __forceinline__ unsigned encf(float f) {
    unsigned u = __float_as_uint(f);
    return (u & 0x80000000u) ? ~u : (u | 0x80000000u);
}
__device__ __forceinline__ float decf(unsigned u) {
    return (u & 0x80000000u) ? __uint_as_float(u & 0x7fffffffu) : __uint_as_float(~u);
}
__device__ __forceinline__ unsigned f2bf(float f) {  // RNE, low 16 bits
    unsigned u = __float_as_uint(f);
    u += 0x7fffu + ((u >> 16) & 1u);
    return u >> 16;
}
__device__ __forceinline__ float bf2f(unsigned h) {
    return __uint_as_float(h << 16);
}
// swizzled word index for [row][32-word] bf16 tiles (row stride 128B)
__device__ __forceinline__ int swz(int row, int w) { return (row << 5) + (w ^ ((row & 7) << 2)); }

// ---------------------------------------------------------------------------
// P1: per-(b,c) sum/max pooling + per-pixel channel mean/max.
// grid = NB*512 (128 px/block), block = 256. Thread (p4=t&31, chb=t>>5)
// reads 8 independent float4s (channels chb+8i) -> full ILP, 16 blocks/CU.
__global__ __launch_bounds__(256) void k_stats(
    const float* __restrict__ x, float* __restrict__ pool_sum,
    unsigned* __restrict__ pool_max, float* __restrict__ s_avg,
    float* __restrict__ s_max)
{
    const int t = threadIdx.x;
    const int b = blockIdx.x >> 9;
    const int pbase = (blockIdx.x & 511) << 7;
    const int p4 = t & 31;     // 4-px group
    const int chb = t >> 5;    // 0..7
    __shared__ float red[16][128];  // rows 0..7 = per-chb px sums, 8..15 = maxes

    float ps0 = 0.f, ps1 = 0.f, ps2 = 0.f, ps3 = 0.f;
    float pm0 = -1e30f, pm1 = -1e30f, pm2 = -1e30f, pm3 = -1e30f;
    float cps[8], cpm[8];
    const size_t base = (size_t)b * CB * HW + pbase + (p4 << 2);
    #pragma unroll
    for (int i = 0; i < 8; ++i) {
        const int c = chb + (i << 3);
        const float4 v = *(const float4*)(x + base + (size_t)c * HW);
        ps0 += v.x; ps1 += v.y; ps2 += v.z; ps3 += v.w;
        pm0 = fmaxf(pm0, v.x); pm1 = fmaxf(pm1, v.y);
        pm2 = fmaxf(pm2, v.z); pm3 = fmaxf(pm3, v.w);
        cps[i] = (v.x + v.y) + (v.z + v.w);
        cpm[i] = fmaxf(fmaxf(v.x, v.y), fmaxf(v.z, v.w));
    }
    *(float4*)&red[chb][p4 << 2]     = make_float4(ps0, ps1, ps2, ps3);
    *(float4*)&red[8 + chb][p4 << 2] = make_float4(pm0, pm1, pm2, pm3);

    // per-channel 128-px totals: 32-lane butterfly (p4 lanes are consecutive)
    #pragma unroll
    for (int i = 0; i < 8; ++i) {
        #pragma unroll
        for (int off = 16; off; off >>= 1) {
            cps[i] += __shfl_xor(cps[i], off);
            cpm[i] = fmaxf(cpm[i], __shfl_xor(cpm[i], off));
        }
    }
    __syncthreads();
    if (t < 128) {            // per-pixel channel mean
        float s = 0.f;
        #pragma unroll
        for (int k = 0; k < 8; ++k) s += red[k][t];
        s_avg[(size_t)b * HW + pbase + t] = s * (1.f / 64.f);
    } else {                  // per-pixel channel max
        const int px = t - 128;
        float m = -1e30f;
        #pragma unroll
        for (int k = 0; k < 8; ++k) m = fmaxf(m, red[8 + k][px]);
        s_max[(size_t)b * HW + pbase + px] = m;
    }
    if ((t & 31) == 0) {
        #pragma unroll
        for (int i = 0; i < 8; ++i) {
            atomicAdd(&pool_sum[(b << 6) + chb + (i << 3)], cps[i]);
            atomicMax(&pool_max[(b << 6) + chb + (i << 3)], encf(cpm[i]));
        }
    }
}

// ---------------------------------------------------------------------------
// P2: 7x7 spatial-attention conv + (row-0 blocks) channel-attention MLP.
__global__ __launch_bounds__(256) void k_sa_ca(
    const float* __restrict__ s_avg, const float* __restrict__ s_max,
    const float* __restrict__ w,
    const float* __restrict__ pool_sum, const unsigned* __restrict__ pool_max,
    const float* __restrict__ w1, const float* __restrict__ w2,
    float* __restrict__ sa, float* __restrict__ ca)
{
    const int t = threadIdx.x;
    const int b = blockIdx.x >> 8;
    const int pix = ((blockIdx.x & 255) << 8) | t;
    const int i = pix >> 8, j = pix & 255;
    float acc = 0.f;
    #pragma unroll
    for (int cin = 0; cin < 2; ++cin) {
        const float* src = (cin ? s_max : s_avg) + (size_t)b * HW;
        const float* wk = w + cin * 49;
        #pragma unroll
        for (int ki = 0; ki < 7; ++ki) {
            const int y = i + ki - 3;
            if ((unsigned)y < 256u) {
                #pragma unroll
                for (int kj = 0; kj < 7; ++kj) {
                    const int xx = j + kj - 3;
                    if ((unsigned)xx < 256u) acc += src[(y << 8) | xx] * wk[ki * 7 + kj];
                }
            }
        }
    }
    sa[(size_t)b * HW + pix] = sigm(acc);

    if ((blockIdx.x & 255) == 0) {   // block-uniform branch: also compute ca[b]
        __shared__ float av[CB], mv[CB], hh[8];
        if (t < CB) {
            av[t] = pool_sum[b * CB + t] * (1.f / (float)HW);
            mv[t] = decf(pool_max[b * CB + t]);
        }
        __syncthreads();
        if (t < 8) {
            const int h = t & 3;
            const float* v = (t < 4) ? av : mv;
            float s = 0;
            for (int c = 0; c < CB; ++c) s += w1[h * CB + c] * v[c];
            hh[t] = fmaxf(s, 0.f);
        }
        __syncthreads();
        if (t < CB) {
            float s = 0;
            #pragma unroll
            for (int h = 0; h < 4; ++h) s += w2[t * 4 + h] * (hh[h] + hh[4 + h]);
            ca[b * CB + t] = sigm(s);
        }
    }
}

// ---------------------------------------------------------------------------
// P4: MFMA main. 128-px tile/block, 4 waves. Outputs d (bf16, [px][64ch]) and
// xpc (bf16 copy of x, [px][64ch]) + GN partial stats.
__global__ __launch_bounds__(256, 3) void k_main(
    const float* __restrict__ x, const float* __restrict__ sa,
    const float* __restrict__ ca, const float* __restrict__ gw,
    const float* __restrict__ dw, const float* __restrict__ db,
    unsigned short* __restrict__ dbuf, unsigned short* __restrict__ xpc,
    float* __restrict__ gn_sum, float* __restrict__ gn_sq)
{
    __shared__ unsigned lds[12320];
    const int t = threadIdx.x;
    const int wv = t >> 6, l = t & 63, hi = l >> 4, lo = l & 15;
    const int b = blockIdx.x >> 9;
    const int pbase = (blockIdx.x & 511) << 7;

    // ---- stage weights: [outch][k] bf16, swizzled ----
    {
        const int orow = t >> 2, cq = (t & 3) << 4;
        const float* gsrc = gw + (orow << 6) + cq;
        const float* dsrc = dw + (orow << 6) + cq;
        unsigned ug[8], ud[8];
        #pragma unroll
        for (int j = 0; j < 8; ++j) {
            ug[j] = f2bf(gsrc[2 * j]) | (f2bf(gsrc[2 * j + 1]) << 16);
            ud[j] = f2bf(dsrc[2 * j]) | (f2bf(dsrc[2 * j + 1]) << 16);
        }
        const int wbase = (t & 3) << 3;
        *(uint4*)&lds[swz(orow, wbase)]            = make_uint4(ug[0], ug[1], ug[2], ug[3]);
        *(uint4*)&lds[swz(orow, wbase + 4)]        = make_uint4(ug[4], ug[5], ug[6], ug[7]);
        *(uint4*)&lds[2048 + swz(orow, wbase)]     = make_uint4(ud[0], ud[1], ud[2], ud[3]);
        *(uint4*)&lds[2048 + swz(orow, wbase + 4)] = make_uint4(ud[4], ud[5], ud[6], ud[7]);
    }

    // ---- stage x (XT @8192) and fuse (FT @4096): [px][ch] bf16, swizzled ----
    {
        const int px0 = l << 1;
        const float2 sv = *(const float2*)(sa + (size_t)b * HW + pbase + px0);
        unsigned ux0[8], ux1[8], uf0[8], uf1[8];
        #pragma unroll
        for (int j2 = 0; j2 < 8; ++j2) {
            const int c0 = (wv << 4) + 2 * j2;
            const float cv0 = ca[(b << 6) + c0];
            const float cv1 = ca[(b << 6) + c0 + 1];
            const float2 v0 = *(const float2*)(x + ((size_t)((b << 6) + c0)) * HW + pbase + px0);
            const float2 v1 = *(const float2*)(x + ((size_t)((b << 6) + c0 + 1)) * HW + pbase + px0);
            ux0[j2] = f2bf(v0.x) | (f2bf(v1.x) << 16);
            ux1[j2] = f2bf(v0.y) | (f2bf(v1.y) << 16);
            uf0[j2] = f2bf(v0.x * (sv.x + cv0)) | (f2bf(v1.x * (sv.x + cv1)) << 16);
            uf1[j2] = f2bf(v0.y * (sv.y + cv0)) | (f2bf(v1.y * (sv.y + cv1)) << 16);
        }
        const int wb = wv << 3;
        *(uint4*)&lds[8192 + swz(px0, wb)]         = make_uint4(ux0[0], ux0[1], ux0[2], ux0[3]);
        *(uint4*)&lds[8192 + swz(px0, wb + 4)]     = make_uint4(ux0[4], ux0[5], ux0[6], ux0[7]);
        *(uint4*)&lds[8192 + swz(px0 + 1, wb)]     = make_uint4(ux1[0], ux1[1], ux1[2], ux1[3]);
        *(uint4*)&lds[8192 + swz(px0 + 1, wb + 4)] = make_uint4(ux1[4], ux1[5], ux1[6], ux1[7]);
        *(uint4*)&lds[4096 + swz(px0, wb)]         = make_uint4(uf0[0], uf0[1], uf0[2], uf0[3]);
        *(uint4*)&lds[4096 + swz(px0, wb + 4)]     = make_uint4(uf0[4], uf0[5], uf0[6], uf0[7]);
        *(uint4*)&lds[4096 + swz(px0 + 1, wb)]     = make_uint4(uf1[0], uf1[1], uf1[2], uf1[3]);
        *(uint4*)&lds[4096 + swz(px0 + 1, wb + 4)] = make_uint4(uf1[4], uf1[5], uf1[6], uf1[7]);
    }
    __syncthreads();

    // ---- GEMM1: guide logits = gate_w @ fuse ----
    f32x4 acc[8];
    #pragma unroll
    for (int n = 0; n < 8; ++n) acc[n] = (f32x4){0.f, 0.f, 0.f, 0.f};
    {
        const int arow = (wv << 4) + lo;
        const s16x8 a0 = __builtin_bit_cast(s16x8, *(const uint4*)&lds[swz(arow, hi << 2)]);
        const s16x8 a1 = __builtin_bit_cast(s16x8, *(const uint4*)&lds[swz(arow, (hi << 2) + 16)]);
        #pragma unroll
        for (int n = 0; n < 8; ++n) {
            const int brow = (n << 4) + lo;
            const s16x8 b0 = __builtin_bit_cast(s16x8, *(const uint4*)&lds[4096 + swz(brow, hi << 2)]);
            const s16x8 b1 = __builtin_bit_cast(s16x8, *(const uint4*)&lds[4096 + swz(brow, (hi << 2) + 16)]);
            acc[n] = __builtin_amdgcn_mfma_f32_16x16x32_bf16(a0, b0, acc[n], 0, 0, 0);
            acc[n] = __builtin_amdgcn_mfma_f32_16x16x32_bf16(a1, b1, acc[n], 0, 0, 0);
        }
    }
    __syncthreads();

    // ---- xg = x * sigmoid(logit) * mask, into FT ----
    {
        const bool row255 = (pbase >> 8) == 255;
        const bool halfblk = (pbase & 128) != 0;
        const int wb2 = (wv << 3) + (hi << 1);
        #pragma unroll
        for (int n = 0; n < 8; ++n) {
            const int pxl = (n << 4) + lo;
            const uint2 xv = *(const uint2*)&lds[8192 + swz(pxl, wb2)];
            const bool zero = row255 || (halfblk && pxl == 127);
            float xg0 = zero ? 0.f : bf2f(xv.x & 0xffffu) * sigm(acc[n][0]);
            float xg1 = zero ? 0.f : bf2f(xv.x >> 16)     * sigm(acc[n][1]);
            float xg2 = zero ? 0.f : bf2f(xv.y & 0xffffu) * sigm(acc[n][2]);
            float xg3 = zero ? 0.f : bf2f(xv.y >> 16)     * sigm(acc[n][3]);
            uint2 o;
            o.x = f2bf(xg0) | (f2bf(xg1) << 16);
            o.y = f2bf(xg2) | (f2bf(xg3) << 16);
            *(uint2*)&lds[4096 + swz(pxl, wb2)] = o;
        }
    }
    __syncthreads();

    // ---- GEMM2: d = dsc_w @ xg ----
    f32x4 acc2[8];
    #pragma unroll
    for (int n = 0; n < 8; ++n) acc2[n] = (f32x4){0.f, 0.f, 0.f, 0.f};
    {
        const int arow = (wv << 4) + lo;
        const s16x8 a0 = __builtin_bit_cast(s16x8, *(const uint4*)&lds[2048 + swz(arow, hi << 2)]);
        const s16x8 a1 = __builtin_bit_cast(s16x8, *(const uint4*)&lds[2048 + swz(arow, (hi << 2) + 16)]);
        #pragma unroll
        for (int n = 0; n < 8; ++n) {
            const int brow = (n << 4) + lo;
            const s16x8 b0 = __builtin_bit_cast(s16x8, *(const uint4*)&lds[4096 + swz(brow, hi << 2)]);
            const s16x8 b1 = __builtin_bit_cast(s16x8, *(const uint4*)&lds[4096 + swz(brow, (hi << 2) + 16)]);
            acc2[n] = __builtin_amdgcn_mfma_f32_16x16x32_bf16(a0, b0, acc2[n], 0, 0, 0);
            acc2[n] = __builtin_amdgcn_mfma_f32_16x16x32_bf16(a1, b1, acc2[n], 0, 0, 0);
        }
    }

    // ---- epilogue: bias + GN partials + direct channel-last d stores ----
    float gs = 0.f, gq = 0.f;
    {
        const float4 bv = *(const float4*)(db + (wv << 4) + (hi << 2));
        unsigned short* dp = dbuf + (((size_t)b * HW + pbase) << 6) + (wv << 4) + (hi << 2);
        #pragma unroll
        for (int n = 0; n < 8; ++n) {
            const int pxl = (n << 4) + lo;
            const float d0 = acc2[n][0] + bv.x, d1 = acc2[n][1] + bv.y;
            const float d2 = acc2[n][2] + bv.z, d3 = acc2[n][3] + bv.w;
            gs += d0 + d1 + d2 + d3;
            gq += d0 * d0 + d1 * d1 + d2 * d2 + d3 * d3;
            uint2 o;
            o.x = f2bf(d0) | (f2bf(d1) << 16);
            o.y = f2bf(d2) | (f2bf(d3) << 16);
            *(uint2*)(dp + ((size_t)pxl << 6)) = o;
        }
    }
    // ---- dump x-tile (XT) as bf16 [px][ch] copy for downstream passes ----
    {
        const int px = t >> 1, hf = t & 1;
        unsigned short* xp = xpc + (((size_t)b * HW + pbase + px) << 6) + (hf << 5);
        #pragma unroll
        for (int q = 0; q < 4; ++q) {
            const uint4 v = *(const uint4*)&lds[8192 + swz(px, (hf << 4) + (q << 2))];
            *(uint4*)(xp + (q << 3)) = v;
        }
    }
    #pragma unroll
    for (int o = 1; o < 16; o <<= 1) { gs += __shfl_xor(gs, o); gq += __shfl_xor(gq, o); }
    float* smf = (float*)&lds[12288];
    if (lo == 0) { smf[(((wv << 2) + hi) << 1)] = gs; smf[(((wv << 2) + hi) << 1) + 1] = gq; }
    __syncthreads();
    if (t < 16) {
        atomicAdd(&gn_sum[(b << 4) + t], smf[2 * t]);
        atomicAdd(&gn_sq[(b << 4) + t],  smf[2 * t + 1]);
    }
}

// ---------------------------------------------------------------------------
// P5: y = relu(GN(d)) + x in-place on dbuf ([px][ch]); GN finalize inlined;
// BN stats into 8-way-spread scratch. grid = 2048 (256 px/block).
__global__ __launch_bounds__(256) void k_gnbn(
    const unsigned short* __restrict__ xpc, unsigned short* __restrict__ dy,
    const float* __restrict__ gn_sum, const float* __restrict__ gn_sq,
    const float* __restrict__ gamma, const float* __restrict__ beta,
    float* __restrict__ bn_scr)
{
    const int t = threadIdx.x;
    const size_t P0 = (size_t)blockIdx.x << 8;
    const int b = (int)(P0 >> 16);
    __shared__ float ga[CB], gb[CB];
    __shared__ float red[4][128];
    if (t < CB) {
        const int g = t >> 2;
        const float n4 = 4.f * (float)HW;
        const float mu = gn_sum[b * 16 + g] / n4;
        const float var = gn_sq[b * 16 + g] / n4 - mu * mu;
        const float a = rsqrtf(var + 1e-5f) * gamma[t];
        ga[t] = a; gb[t] = beta[t] - mu * a;
    }
    __syncthreads();
    const int o8 = (t & 7) << 3;
    float ar[8], br[8];
    #pragma unroll
    for (int k = 0; k < 8; ++k) { ar[k] = ga[o8 + k]; br[k] = gb[o8 + k]; }
    float as[8], aq[8];
    #pragma unroll
    for (int k = 0; k < 8; ++k) { as[k] = 0.f; aq[k] = 0.f; }
    for (int i = 0; i < 8; ++i) {
        const size_t P = P0 + (i << 5) + (t >> 3);
        const size_t idx = (P << 6) + o8;
        const uint4 dv = *(const uint4*)(dy + idx);
        const uint4 xv = *(const uint4*)(xpc + idx);
        const unsigned dw_[4] = {dv.x, dv.y, dv.z, dv.w};
        const unsigned xw_[4] = {xv.x, xv.y, xv.z, xv.w};
        uint4 o;
        unsigned ow_[4];
        #pragma unroll
        for (int p = 0; p < 4; ++p) {
            const int k0 = 2 * p;
            const float y0 = fmaxf(bf2f(dw_[p] & 0xffffu) * ar[k0] + br[k0], 0.f) + bf2f(xw_[p] & 0xffffu);
            const float y1 = fmaxf(bf2f(dw_[p] >> 16) * ar[k0 + 1] + br[k0 + 1], 0.f) + bf2f(xw_[p] >> 16);
            as[k0] += y0; aq[k0] += y0 * y0;
            as[k0 + 1] += y1; aq[k0 + 1] += y1 * y1;
            ow_[p] = f2bf(y0) | (f2bf(y1) << 16);
        }
        o.x = ow_[0]; o.y = ow_[1]; o.z = ow_[2]; o.w = ow_[3];
        *(uint4*)(dy + idx) = o;
    }
    #pragma unroll
    for (int k = 0; k < 8; ++k) {
        #pragma unroll
        for (int m = 8; m < 64; m <<= 1) {
            as[k] += __shfl_xor(as[k], m);
            aq[k] += __shfl_xor(aq[k], m);
        }
    }
    if ((t & 63) < 8) {
        const int o = t & 7, wvv = t >> 6;
        #pragma unroll
        for (int k = 0; k < 8; ++k) {
            red[wvv][o * 16 + k] = as[k];
            red[wvv][o * 16 + 8 + k] = aq[k];
        }
    }
    __syncthreads();
    if (t < 128) {
        const int o = t >> 4, st = (t >> 3) & 1, k = t & 7;
        const float v = red[0][t] + red[1][t] + red[2][t] + red[3][t];
        atomicAdd(&bn_scr[(blockIdx.x & 7) * 128 + st * 64 + o * 8 + k], v);
    }
}

// ---------------------------------------------------------------------------
// P6: out = ob + sum_c ow[c]*prelu(BN(y)); BN finalize inlined. grid = 2048.
__global__ __launch_bounds__(256) void k_out(
    const unsigned short* __restrict__ y, const float* __restrict__ bn_scr,
    const float* __restrict__ gamma, const float* __restrict__ beta,
    const float* __restrict__ pa, const float* __restrict__ ow,
    const float* __restrict__ ob, float* __restrict__ out)
{
    const int t = threadIdx.x;
    __shared__ float A[CB], Bs[CB], W[CB];
    if (t < CB) {
        float s = 0.f, q = 0.f;
        #pragma unroll
        for (int r = 0; r < 8; ++r) { s += bn_scr[r * 128 + t]; q += bn_scr[r * 128 + 64 + t]; }
        const float n = (float)NB * (float)HW;
        const float mu = s / n;
        const float var = q / n - mu * mu;
        const float a = rsqrtf(var + 1e-5f) * gamma[t];
        A[t] = a; Bs[t] = beta[t] - mu * a; W[t] = ow[t];
    }
    __syncthreads();
    const size_t P = ((size_t)blockIdx.x << 8) + t;
    const unsigned short* yp = y + (P << 6);
    const float alpha = pa[0];
    float acc = ob[0];
    #pragma unroll
    for (int q = 0; q < 8; ++q) {   // 8 x uint4 = 64 bf16 channels per pixel
        const uint4 v = *(const uint4*)(yp + (q << 3));
        const unsigned vw[4] = {v.x, v.y, v.z, v.w};
        #pragma unroll
        for (int p = 0; p < 4; ++p) {
            const int c = (q << 3) + 2 * p;
            float z0 = bf2f(vw[p] & 0xffffu) * A[c] + Bs[c];
            float z1 = bf2f(vw[p] >> 16) * A[c + 1] + Bs[c + 1];
            z0 = z0 >= 0.f ? z0 : alpha * z0;
            z1 = z1 >= 0.f ? z1 : alpha * z1;
            acc += W[c] * z0 + W[c + 1] * z1;
        }
    }
    out[P] = acc;
}

// ---------------------------------------------------------------------------
extern "C" void kernel_launch(void* const* d_in, const int* in_sizes, int n_in,
                              void* d_out, int out_size, void* d_ws, size_t ws_size,
                              hipStream_t stream)
{
    const float* x        = (const float*)d_in[0];
    const float* ca_w1    = (const float*)d_in[1];
    const float* ca_w2    = (const float*)d_in[2];
    const float* sa_w     = (const float*)d_in[3];
    const float* gate_w   = (const float*)d_in[4];
    // d_in[5..8]: offset branch — dead in forward math, skipped
    const float* dsc_w    = (const float*)d_in[9];
    const float* dsc_b    = (const float*)d_in[10];
    const float* gn_gamma = (const float*)d_in[11];
    const float* gn_beta  = (const float*)d_in[12];
    const float* bn_gamma = (const float*)d_in[13];
    const float* bn_beta  = (const float*)d_in[14];
    const float* prelu_a  = (const float*)d_in[15];
    const float* out_w    = (const float*)d_in[16];
    const float* out_b    = (const float*)d_in[17];
    float* out = (float*)d_out;

    char* ws = (char*)d_ws;
    size_t off = 0;
    auto alloc = [&](size_t bytes) -> char* {
        char* p = ws + off;
        off = (off + bytes + 255) & ~(size_t)255;
        return p;
    };
    unsigned short* dbuf = (unsigned short*)alloc((size_t)NB * HW * CB * 2);  // d -> y, [px][ch]
    unsigned short* xpc  = (unsigned short*)alloc((size_t)NB * HW * CB * 2);  // bf16 x, [px][ch]
    float* s_avg = (float*)alloc((size_t)NB * HW * 4);
    float* s_max = (float*)alloc((size_t)NB * HW * 4);
    float* sa    = (float*)alloc((size_t)NB * HW * 4);
    float* cav   = (float*)alloc(512 * 4);
    char* stats  = alloc(2304 * 4);   // contiguous zeroed accumulators
    float*    pool_sum = (float*)stats;
    unsigned* pool_max = (unsigned*)(stats + 512 * 4);
    float*    gn_sum   = (float*)(stats + 1024 * 4);
    float*    gn_sq    = (float*)(stats + 1152 * 4);
    float*    bn_scr   = (float*)(stats + 1280 * 4);  // [8][128]
    (void)in_sizes; (void)n_in; (void)out_size; (void)ws_size;

    hipMemsetAsync(stats, 0, 2304 * 4, stream);

    k_stats<<<NB * 512, 256, 0, stream>>>(x, pool_sum, pool_max, s_avg, s_max);
    k_sa_ca<<<NB * 256, 256, 0, stream>>>(s_avg, s_max, sa_w, pool_sum, pool_max,
                                          ca_w1, ca_w2, sa, cav);
    k_main <<<NB * 512, 256, 0, stream>>>(x, sa, cav, gate_w, dsc_w, dsc_b,
                                          dbuf, xpc, gn_sum, gn_sq);
    k_gnbn <<<2048,     256, 0, stream>>>(xpc, dbuf, gn_sum, gn_sq, gn_gamma, gn_beta, bn_scr);
    k_out  <<<2048,     256, 0, stream>>>(dbuf, bn_scr, bn_gamma, bn_beta,
                                          prelu_a, out_w, out_b, out);
}

// Round 6
// 214.639 us; speedup vs baseline: 1.7499x; 1.7499x over previous
//
#include <hip/hip_runtime.h>

#define HW 65536
#define CB 64
#define NB 8

typedef __attribute__((ext_vector_type(4))) float f32x4;
typedef __attribute__((ext_vector_type(8))) short s16x8;

__device__ __forceinline__ float sigm(float v) { return 1.f / (1.f + __expf(-v)); }

__device__ __forceinline__ unsigned encf(float f) {
    unsigned u = __float_as_uint(f);
    return (u & 0x80000000u) ? ~u : (u | 0x80000000u);
}
__device__ __forceinline__ float decf(unsigned u) {
    return (u & 0x80000000u) ? __uint_as_float(u & 0x7fffffffu) : __uint_as_float(~u);
}
__device__ __forceinline__ unsigned f2bf(float f) {  // RNE, low 16 bits
    unsigned u = __float_as_uint(f);
    u += 0x7fffu + ((u >> 16) & 1u);
    return u >> 16;
}
__device__ __forceinline__ float bf2f(unsigned h) {
    return __uint_as_float(h << 16);
}
// swizzled word index for [row][32-word] bf16 tiles (row stride 128B)
__device__ __forceinline__ int swz(int row, int w) { return (row << 5) + (w ^ ((row & 7) << 2)); }

// ---------------------------------------------------------------------------
// P1: per-(b,c) sum/max pooling + per-pixel channel mean/max.
// grid = NB*128 (512 px/block as 4x128 sub-tiles), block = 256.
// Mirrors k_main's proven staging pattern: wave wv owns 16 channels; thread
// issues 16 independent float2 loads per sub-tile (explicit array -> all in
// flight). Per-channel partials accumulate in regs across sub-tiles; one
// butterfly + 16 atomics/wave at the end, spread over 4 scratch copies.
__global__ __launch_bounds__(256) void k_stats(
    const float* __restrict__ x, float* __restrict__ pool_scr,
    unsigned* __restrict__ pmax_scr, float* __restrict__ s_avg,
    float* __restrict__ s_max)
{
    const int t = threadIdx.x;
    const int wv = t >> 6, l = t & 63;
    const int b = blockIdx.x >> 7;
    const int pbase = (blockIdx.x & 127) << 9;
    const int px0 = l << 1;
    __shared__ float redS[4][128];
    __shared__ float redM[4][128];
    float cs[16], cm[16];
    #pragma unroll
    for (int j = 0; j < 16; ++j) { cs[j] = 0.f; cm[j] = -1e30f; }
    const size_t cbase = ((size_t)(b << 6) + (wv << 4)) * HW;
    for (int it = 0; it < 4; ++it) {
        const int pb = pbase + (it << 7);
        float2 v[16];
        #pragma unroll
        for (int j = 0; j < 16; ++j)
            v[j] = *(const float2*)(x + cbase + (size_t)j * HW + pb + px0);
        float s0 = 0.f, s1 = 0.f, m0 = -1e30f, m1 = -1e30f;
        #pragma unroll
        for (int j = 0; j < 16; ++j) {
            s0 += v[j].x; s1 += v[j].y;
            m0 = fmaxf(m0, v[j].x); m1 = fmaxf(m1, v[j].y);
            cs[j] += v[j].x + v[j].y;
            cm[j] = fmaxf(cm[j], fmaxf(v[j].x, v[j].y));
        }
        *(float2*)&redS[wv][px0] = make_float2(s0, s1);
        *(float2*)&redM[wv][px0] = make_float2(m0, m1);
        __syncthreads();
        if (t < 128) {
            s_avg[(size_t)b * HW + pb + t] =
                (redS[0][t] + redS[1][t] + redS[2][t] + redS[3][t]) * (1.f / 64.f);
        } else {
            const int px = t - 128;
            s_max[(size_t)b * HW + pb + px] =
                fmaxf(fmaxf(redM[0][px], redM[1][px]), fmaxf(redM[2][px], redM[3][px]));
        }
        __syncthreads();
    }
    #pragma unroll
    for (int j = 0; j < 16; ++j) {
        #pragma unroll
        for (int off = 32; off; off >>= 1) {
            cs[j] += __shfl_xor(cs[j], off);
            cm[j] = fmaxf(cm[j], __shfl_xor(cm[j], off));
        }
    }
    if (l == 0) {
        const int cp = ((blockIdx.x & 3) << 6) + (wv << 4);
        #pragma unroll
        for (int j = 0; j < 16; ++j) {
            atomicAdd(&pool_scr[(b << 8) + cp + j], cs[j]);
            atomicMax(&pmax_scr[(b << 8) + cp + j], encf(cm[j]));
        }
    }
}

// ---------------------------------------------------------------------------
// P2: 7x7 spatial-attention conv + (row-0 blocks) channel-attention MLP.
__global__ __launch_bounds__(256) void k_sa_ca(
    const float* __restrict__ s_avg, const float* __restrict__ s_max,
    const float* __restrict__ w,
    const float* __restrict__ pool_scr, const unsigned* __restrict__ pmax_scr,
    const float* __restrict__ w1, const float* __restrict__ w2,
    float* __restrict__ sa, float* __restrict__ ca)
{
    const int t = threadIdx.x;
    const int b = blockIdx.x >> 8;
    const int pix = ((blockIdx.x & 255) << 8) | t;
    const int i = pix >> 8, j = pix & 255;
    float acc = 0.f;
    #pragma unroll
    for (int cin = 0; cin < 2; ++cin) {
        const float* src = (cin ? s_max : s_avg) + (size_t)b * HW;
        const float* wk = w + cin * 49;
        #pragma unroll
        for (int ki = 0; ki < 7; ++ki) {
            const int y = i + ki - 3;
            if ((unsigned)y < 256u) {
                #pragma unroll
                for (int kj = 0; kj < 7; ++kj) {
                    const int xx = j + kj - 3;
                    if ((unsigned)xx < 256u) acc += src[(y << 8) | xx] * wk[ki * 7 + kj];
                }
            }
        }
    }
    sa[(size_t)b * HW + pix] = sigm(acc);

    if ((blockIdx.x & 255) == 0) {   // block-uniform branch: also compute ca[b]
        __shared__ float av[CB], mv[CB], hh[8];
        if (t < CB) {
            const float s = pool_scr[(b << 8) + t] + pool_scr[(b << 8) + 64 + t] +
                            pool_scr[(b << 8) + 128 + t] + pool_scr[(b << 8) + 192 + t];
            const unsigned m = max(max(pmax_scr[(b << 8) + t], pmax_scr[(b << 8) + 64 + t]),
                                   max(pmax_scr[(b << 8) + 128 + t], pmax_scr[(b << 8) + 192 + t]));
            av[t] = s * (1.f / (float)HW);
            mv[t] = decf(m);
        }
        __syncthreads();
        if (t < 8) {
            const int h = t & 3;
            const float* v = (t < 4) ? av : mv;
            float s = 0;
            for (int c = 0; c < CB; ++c) s += w1[h * CB + c] * v[c];
            hh[t] = fmaxf(s, 0.f);
        }
        __syncthreads();
        if (t < CB) {
            float s = 0;
            #pragma unroll
            for (int h = 0; h < 4; ++h) s += w2[t * 4 + h] * (hh[h] + hh[4 + h]);
            ca[b * CB + t] = sigm(s);
        }
    }
}

// ---------------------------------------------------------------------------
// P4: MFMA main. 128-px tile/block, 4 waves. Outputs d (bf16, [px][64ch]) and
// xpc (bf16 copy of x, [px][64ch]) + GN partial stats.
__global__ __launch_bounds__(256, 3) void k_main(
    const float* __restrict__ x, const float* __restrict__ sa,
    const float* __restrict__ ca, const float* __restrict__ gw,
    const float* __restrict__ dw, const float* __restrict__ db,
    unsigned short* __restrict__ dbuf, unsigned short* __restrict__ xpc,
    float* __restrict__ gn_sum, float* __restrict__ gn_sq)
{
    __shared__ unsigned lds[12320];
    const int t = threadIdx.x;
    const int wv = t >> 6, l = t & 63, hi = l >> 4, lo = l & 15;
    const int b = blockIdx.x >> 9;
    const int pbase = (blockIdx.x & 511) << 7;

    // ---- stage weights: [outch][k] bf16, swizzled ----
    {
        const int orow = t >> 2, cq = (t & 3) << 4;
        const float* gsrc = gw + (orow << 6) + cq;
        const float* dsrc = dw + (orow << 6) + cq;
        unsigned ug[8], ud[8];
        #pragma unroll
        for (int j = 0; j < 8; ++j) {
            ug[j] = f2bf(gsrc[2 * j]) | (f2bf(gsrc[2 * j + 1]) << 16);
            ud[j] = f2bf(dsrc[2 * j]) | (f2bf(dsrc[2 * j + 1]) << 16);
        }
        const int wbase = (t & 3) << 3;
        *(uint4*)&lds[swz(orow, wbase)]            = make_uint4(ug[0], ug[1], ug[2], ug[3]);
        *(uint4*)&lds[swz(orow, wbase + 4)]        = make_uint4(ug[4], ug[5], ug[6], ug[7]);
        *(uint4*)&lds[2048 + swz(orow, wbase)]     = make_uint4(ud[0], ud[1], ud[2], ud[3]);
        *(uint4*)&lds[2048 + swz(orow, wbase + 4)] = make_uint4(ud[4], ud[5], ud[6], ud[7]);
    }

    // ---- stage x (XT @8192) and fuse (FT @4096): [px][ch] bf16, swizzled ----
    {
        const int px0 = l << 1;
        const float2 sv = *(const float2*)(sa + (size_t)b * HW + pbase + px0);
        unsigned ux0[8], ux1[8], uf0[8], uf1[8];
        #pragma unroll
        for (int j2 = 0; j2 < 8; ++j2) {
            const int c0 = (wv << 4) + 2 * j2;
            const float cv0 = ca[(b << 6) + c0];
            const float cv1 = ca[(b << 6) + c0 + 1];
            const float2 v0 = *(const float2*)(x + ((size_t)((b << 6) + c0)) * HW + pbase + px0);
            const float2 v1 = *(const float2*)(x + ((size_t)((b << 6) + c0 + 1)) * HW + pbase + px0);
            ux0[j2] = f2bf(v0.x) | (f2bf(v1.x) << 16);
            ux1[j2] = f2bf(v0.y) | (f2bf(v1.y) << 16);
            uf0[j2] = f2bf(v0.x * (sv.x + cv0)) | (f2bf(v1.x * (sv.x + cv1)) << 16);
            uf1[j2] = f2bf(v0.y * (sv.y + cv0)) | (f2bf(v1.y * (sv.y + cv1)) << 16);
        }
        const int wb = wv << 3;
        *(uint4*)&lds[8192 + swz(px0, wb)]         = make_uint4(ux0[0], ux0[1], ux0[2], ux0[3]);
        *(uint4*)&lds[8192 + swz(px0, wb + 4)]     = make_uint4(ux0[4], ux0[5], ux0[6], ux0[7]);
        *(uint4*)&lds[8192 + swz(px0 + 1, wb)]     = make_uint4(ux1[0], ux1[1], ux1[2], ux1[3]);
        *(uint4*)&lds[8192 + swz(px0 + 1, wb + 4)] = make_uint4(ux1[4], ux1[5], ux1[6], ux1[7]);
        *(uint4*)&lds[4096 + swz(px0, wb)]         = make_uint4(uf0[0], uf0[1], uf0[2], uf0[3]);
        *(uint4*)&lds[4096 + swz(px0, wb + 4)]     = make_uint4(uf0[4], uf0[5], uf0[6], uf0[7]);
        *(uint4*)&lds[4096 + swz(px0 + 1, wb)]     = make_uint4(uf1[0], uf1[1], uf1[2], uf1[3]);
        *(uint4*)&lds[4096 + swz(px0 + 1, wb + 4)] = make_uint4(uf1[4], uf1[5], uf1[6], uf1[7]);
    }
    __syncthreads();

    // ---- GEMM1: guide logits = gate_w @ fuse ----
    f32x4 acc[8];
    #pragma unroll
    for (int n = 0; n < 8; ++n) acc[n] = (f32x4){0.f, 0.f, 0.f, 0.f};
    {
        const int arow = (wv << 4) + lo;
        const s16x8 a0 = __builtin_bit_cast(s16x8, *(const uint4*)&lds[swz(arow, hi << 2)]);
        const s16x8 a1 = __builtin_bit_cast(s16x8, *(const uint4*)&lds[swz(arow, (hi << 2) + 16)]);
        #pragma unroll
        for (int n = 0; n < 8; ++n) {
            const int brow = (n << 4) + lo;
            const s16x8 b0 = __builtin_bit_cast(s16x8, *(const uint4*)&lds[4096 + swz(brow, hi << 2)]);
            const s16x8 b1 = __builtin_bit_cast(s16x8, *(const uint4*)&lds[4096 + swz(brow, (hi << 2) + 16)]);
            acc[n] = __builtin_amdgcn_mfma_f32_16x16x32_bf16(a0, b0, acc[n], 0, 0, 0);
            acc[n] = __builtin_amdgcn_mfma_f32_16x16x32_bf16(a1, b1, acc[n], 0, 0, 0);
        }
    }
    __syncthreads();

    // ---- xg = x * sigmoid(logit) * mask, into FT ----
    {
        const bool row255 = (pbase >> 8) == 255;
        const bool halfblk = (pbase & 128) != 0;
        const int wb2 = (wv << 3) + (hi << 1);
        #pragma unroll
        for (int n = 0; n < 8; ++n) {
            const int pxl = (n << 4) + lo;
            const uint2 xv = *(const uint2*)&lds[8192 + swz(pxl, wb2)];
            const bool zero = row255 || (halfblk && pxl == 127);
            float xg0 = zero ? 0.f : bf2f(xv.x & 0xffffu) * sigm(acc[n][0]);
            float xg1 = zero ? 0.f : bf2f(xv.x >> 16)     * sigm(acc[n][1]);
            float xg2 = zero ? 0.f : bf2f(xv.y & 0xffffu) * sigm(acc[n][2]);
            float xg3 = zero ? 0.f : bf2f(xv.y >> 16)     * sigm(acc[n][3]);
            uint2 o;
            o.x = f2bf(xg0) | (f2bf(xg1) << 16);
            o.y = f2bf(xg2) | (f2bf(xg3) << 16);
            *(uint2*)&lds[4096 + swz(pxl, wb2)] = o;
        }
    }
    __syncthreads();

    // ---- GEMM2: d = dsc_w @ xg ----
    f32x4 acc2[8];
    #pragma unroll
    for (int n = 0; n < 8; ++n) acc2[n] = (f32x4){0.f, 0.f, 0.f, 0.f};
    {
        const int arow = (wv << 4) + lo;
        const s16x8 a0 = __builtin_bit_cast(s16x8, *(const uint4*)&lds[2048 + swz(arow, hi << 2)]);
        const s16x8 a1 = __builtin_bit_cast(s16x8, *(const uint4*)&lds[2048 + swz(arow, (hi << 2) + 16)]);
        #pragma unroll
        for (int n = 0; n < 8; ++n) {
            const int brow = (n << 4) + lo;
            const s16x8 b0 = __builtin_bit_cast(s16x8, *(const uint4*)&lds[4096 + swz(brow, hi << 2)]);
            const s16x8 b1 = __builtin_bit_cast(s16x8, *(const uint4*)&lds[4096 + swz(brow, (hi << 2) + 16)]);
            acc2[n] = __builtin_amdgcn_mfma_f32_16x16x32_bf16(a0, b0, acc2[n], 0, 0, 0);
            acc2[n] = __builtin_amdgcn_mfma_f32_16x16x32_bf16(a1, b1, acc2[n], 0, 0, 0);
        }
    }

    // ---- epilogue: bias + GN partials + direct channel-last d stores ----
    float gs = 0.f, gq = 0.f;
    {
        const float4 bv = *(const float4*)(db + (wv << 4) + (hi << 2));
        unsigned short* dp = dbuf + (((size_t)b * HW + pbase) << 6) + (wv << 4) + (hi << 2);
        #pragma unroll
        for (int n = 0; n < 8; ++n) {
            const int pxl = (n << 4) + lo;
            const float d0 = acc2[n][0] + bv.x, d1 = acc2[n][1] + bv.y;
            const float d2 = acc2[n][2] + bv.z, d3 = acc2[n][3] + bv.w;
            gs += d0 + d1 + d2 + d3;
            gq += d0 * d0 + d1 * d1 + d2 * d2 + d3 * d3;
            uint2 o;
            o.x = f2bf(d0) | (f2bf(d1) << 16);
            o.y = f2bf(d2) | (f2bf(d3) << 16);
            *(uint2*)(dp + ((size_t)pxl << 6)) = o;
        }
    }
    // ---- dump x-tile (XT) as bf16 [px][ch] copy for downstream passes ----
    {
        const int px = t >> 1, hf = t & 1;
        unsigned short* xp = xpc + (((size_t)b * HW + pbase + px) << 6) + (hf << 5);
        #pragma unroll
        for (int q = 0; q < 4; ++q) {
            const uint4 v = *(const uint4*)&lds[8192 + swz(px, (hf << 4) + (q << 2))];
            *(uint4*)(xp + (q << 3)) = v;
        }
    }
    #pragma unroll
    for (int o = 1; o < 16; o <<= 1) { gs += __shfl_xor(gs, o); gq += __shfl_xor(gq, o); }
    float* smf = (float*)&lds[12288];
    if (lo == 0) { smf[(((wv << 2) + hi) << 1)] = gs; smf[(((wv << 2) + hi) << 1) + 1] = gq; }
    __syncthreads();
    if (t < 16) {
        atomicAdd(&gn_sum[(b << 4) + t], smf[2 * t]);
        atomicAdd(&gn_sq[(b << 4) + t],  smf[2 * t + 1]);
    }
}

// ---------------------------------------------------------------------------
// P5: y = relu(GN(d)) + x in-place on dbuf ([px][ch]); GN finalize inlined;
// BN stats into 8-way-spread scratch. grid = 2048 (256 px/block).
__global__ __launch_bounds__(256) void k_gnbn(
    const unsigned short* __restrict__ xpc, unsigned short* __restrict__ dy,
    const float* __restrict__ gn_sum, const float* __restrict__ gn_sq,
    const float* __restrict__ gamma, const float* __restrict__ beta,
    float* __restrict__ bn_scr)
{
    const int t = threadIdx.x;
    const size_t P0 = (size_t)blockIdx.x << 8;
    const int b = (int)(P0 >> 16);
    __shared__ float ga[CB], gb[CB];
    __shared__ float red[4][128];
    if (t < CB) {
        const int g = t >> 2;
        const float n4 = 4.f * (float)HW;
        const float mu = gn_sum[b * 16 + g] / n4;
        const float var = gn_sq[b * 16 + g] / n4 - mu * mu;
        const float a = rsqrtf(var + 1e-5f) * gamma[t];
        ga[t] = a; gb[t] = beta[t] - mu * a;
    }
    __syncthreads();
    const int o8 = (t & 7) << 3;
    float ar[8], br[8];
    #pragma unroll
    for (int k = 0; k < 8; ++k) { ar[k] = ga[o8 + k]; br[k] = gb[o8 + k]; }
    float as[8], aq[8];
    #pragma unroll
    for (int k = 0; k < 8; ++k) { as[k] = 0.f; aq[k] = 0.f; }
    for (int i = 0; i < 8; ++i) {
        const size_t P = P0 + (i << 5) + (t >> 3);
        const size_t idx = (P << 6) + o8;
        const uint4 dv = *(const uint4*)(dy + idx);
        const uint4 xv = *(const uint4*)(xpc + idx);
        const unsigned dw_[4] = {dv.x, dv.y, dv.z, dv.w};
        const unsigned xw_[4] = {xv.x, xv.y, xv.z, xv.w};
        uint4 o;
        unsigned ow_[4];
        #pragma unroll
        for (int p = 0; p < 4; ++p) {
            const int k0 = 2 * p;
            const float y0 = fmaxf(bf2f(dw_[p] & 0xffffu) * ar[k0] + br[k0], 0.f) + bf2f(xw_[p] & 0xffffu);
            const float y1 = fmaxf(bf2f(dw_[p] >> 16) * ar[k0 + 1] + br[k0 + 1], 0.f) + bf2f(xw_[p] >> 16);
            as[k0] += y0; aq[k0] += y0 * y0;
            as[k0 + 1] += y1; aq[k0 + 1] += y1 * y1;
            ow_[p] = f2bf(y0) | (f2bf(y1) << 16);
        }
        o.x = ow_[0]; o.y = ow_[1]; o.z = ow_[2]; o.w = ow_[3];
        *(uint4*)(dy + idx) = o;
    }
    #pragma unroll
    for (int k = 0; k < 8; ++k) {
        #pragma unroll
        for (int m = 8; m < 64; m <<= 1) {
            as[k] += __shfl_xor(as[k], m);
            aq[k] += __shfl_xor(aq[k], m);
        }
    }
    if ((t & 63) < 8) {
        const int o = t & 7, wvv = t >> 6;
        #pragma unroll
        for (int k = 0; k < 8; ++k) {
            red[wvv][o * 16 + k] = as[k];
            red[wvv][o * 16 + 8 + k] = aq[k];
        }
    }
    __syncthreads();
    if (t < 128) {
        const int o = t >> 4, st = (t >> 3) & 1, k = t & 7;
        const float v = red[0][t] + red[1][t] + red[2][t] + red[3][t];
        atomicAdd(&bn_scr[(blockIdx.x & 7) * 128 + st * 64 + o * 8 + k], v);
    }
}

// ---------------------------------------------------------------------------
// P6: out = ob + sum_c ow[c]*prelu(BN(y)); BN finalize inlined. grid = 2048.
__global__ __launch_bounds__(256) void k_out(
    const unsigned short* __restrict__ y, const float* __restrict__ bn_scr,
    const float* __restrict__ gamma, const float* __restrict__ beta,
    const float* __restrict__ pa, const float* __restrict__ ow,
    const float* __restrict__ ob, float* __restrict__ out)
{
    const int t = threadIdx.x;
    __shared__ float A[CB], Bs[CB], W[CB];
    if (t < CB) {
        float s = 0.f, q = 0.f;
        #pragma unroll
        for (int r = 0; r < 8; ++r) { s += bn_scr[r * 128 + t]; q += bn_scr[r * 128 + 64 + t]; }
        const float n = (float)NB * (float)HW;
        const float mu = s / n;
        const float var = q / n - mu * mu;
        const float a = rsqrtf(var + 1e-5f) * gamma[t];
        A[t] = a; Bs[t] = beta[t] - mu * a; W[t] = ow[t];
    }
    __syncthreads();
    const size_t P = ((size_t)blockIdx.x << 8) + t;
    const unsigned short* yp = y + (P << 6);
    const float alpha = pa[0];
    float acc = ob[0];
    #pragma unroll
    for (int q = 0; q < 8; ++q) {   // 8 x uint4 = 64 bf16 channels per pixel
        const uint4 v = *(const uint4*)(yp + (q << 3));
        const unsigned vw[4] = {v.x, v.y, v.z, v.w};
        #pragma unroll
        for (int p = 0; p < 4; ++p) {
            const int c = (q << 3) + 2 * p;
            float z0 = bf2f(vw[p] & 0xffffu) * A[c] + Bs[c];
            float z1 = bf2f(vw[p] >> 16) * A[c + 1] + Bs[c + 1];
            z0 = z0 >= 0.f ? z0 : alpha * z0;
            z1 = z1 >= 0.f ? z1 : alpha * z1;
            acc += W[c] * z0 + W[c + 1] * z1;
        }
    }
    out[P] = acc;
}

// ---------------------------------------------------------------------------
extern "C" void kernel_launch(void* const* d_in, const int* in_sizes, int n_in,
                              void* d_out, int out_size, void* d_ws, size_t ws_size,
                              hipStream_t stream)
{
    const float* x        = (const float*)d_in[0];
    const float* ca_w1    = (const float*)d_in[1];
    const float* ca_w2    = (const float*)d_in[2];
    const float* sa_w     = (const float*)d_in[3];
    const float* gate_w   = (const float*)d_in[4];
    // d_in[5..8]: offset branch — dead in forward math, skipped
    const float* dsc_w    = (const float*)d_in[9];
    const float* dsc_b    = (const float*)d_in[10];
    const float* gn_gamma = (const float*)d_in[11];
    const float* gn_beta  = (const float*)d_in[12];
    const float* bn_gamma = (const float*)d_in[13];
    const float* bn_beta  = (const float*)d_in[14];
    const float* prelu_a  = (const float*)d_in[15];
    const float* out_w    = (const float*)d_in[16];
    const float* out_b    = (const float*)d_in[17];
    float* out = (float*)d_out;

    char* ws = (char*)d_ws;
    size_t off = 0;
    auto alloc = [&](size_t bytes) -> char* {
        char* p = ws + off;
        off = (off + bytes + 255) & ~(size_t)255;
        return p;
    };
    unsigned short* dbuf = (unsigned short*)alloc((size_t)NB * HW * CB * 2);  // d -> y, [px][ch]
    unsigned short* xpc  = (unsigned short*)alloc((size_t)NB * HW * CB * 2);  // bf16 x, [px][ch]
    float* s_avg = (float*)alloc((size_t)NB * HW * 4);
    float* s_max = (float*)alloc((size_t)NB * HW * 4);
    float* sa    = (float*)alloc((size_t)NB * HW * 4);
    float* cav   = (float*)alloc(512 * 4);
    char* stats  = alloc(5504 * 4);   // contiguous zeroed accumulators
    float*    pool_scr = (float*)stats;                      // [NB][4][64] sums
    unsigned* pmax_scr = (unsigned*)(stats + 2048 * 4);      // [NB][4][64] maxes
    float*    gn_sum   = (float*)(stats + 4096 * 4);         // [NB][16]
    float*    gn_sq    = (float*)(stats + 4224 * 4);         // [NB][16]
    float*    bn_scr   = (float*)(stats + 4352 * 4);         // [8][128]
    (void)in_sizes; (void)n_in; (void)out_size; (void)ws_size;

    hipMemsetAsync(stats, 0, 5504 * 4, stream);

    k_stats<<<NB * 128, 256, 0, stream>>>(x, pool_scr, pmax_scr, s_avg, s_max);
    k_sa_ca<<<NB * 256, 256, 0, stream>>>(s_avg, s_max, sa_w, pool_scr, pmax_scr,
                                          ca_w1, ca_w2, sa, cav);
    k_main <<<NB * 512, 256, 0, stream>>>(x, sa, cav, gate_w, dsc_w, dsc_b,
                                          dbuf, xpc, gn_sum, gn_sq);
    k_gnbn <<<2048,     256, 0, stream>>>(xpc, dbuf, gn_sum, gn_sq, gn_gamma, gn_beta, bn_scr);
    k_out  <<<2048,     256, 0, stream>>>(dbuf, bn_scr, bn_gamma, bn_beta,
                                          prelu_a, out_w, out_b, out);
}

// Round 7
// 176.724 us; speedup vs baseline: 2.1253x; 1.2145x over previous
//
#include <hip/hip_runtime.h>

#define HW 65536
#define CB 64
#define NB 8

typedef __attribute__((ext_vector_type(4))) float f32x4;
typedef __attribute__((ext_vector_type(8))) short s16x8;

__device__ __forceinline__ float sigm(float v) { return 1.f / (1.f + __expf(-v)); }

__device__ __forceinline__ unsigned encf(float f) {
    unsigned u = __float_as_uint(f);
    return (u & 0x80000000u) ? ~u : (u | 0x80000000u);
}
__device__ __forceinline__ float decf(unsigned u) {
    return (u & 0x80000000u) ? __uint_as_float(u & 0x7fffffffu) : __uint_as_float(~u);
}
__device__ __forceinline__ unsigned f2bf(float f) {  // RNE, low 16 bits
    unsigned u = __float_as_uint(f);
    u += 0x7fffu + ((u >> 16) & 1u);
    return u >> 16;
}
__device__ __forceinline__ float bf2f(unsigned h) {
    return __uint_as_float(h << 16);
}
// swizzled word index for [row][32-word] bf16 tiles (row stride 128B)
__device__ __forceinline__ int swz(int row, int w) { return (row << 5) + (w ^ ((row & 7) << 2)); }

// ---------------------------------------------------------------------------
// P1 (k_pre): one pass over fp32 x ->
//   s_avg/s_max (per-px channel mean/max, in-register),
//   xpc (bf16 [px][64ch] copy via swizzled LDS transpose, coalesced dump),
//   per-channel pool sum/max partials (transposed LDS re-read, 8-way scratch).
// grid = NB*256 (256 px/block), block = 256 (thread == pixel).
__global__ __launch_bounds__(256) void k_pre(
    const float* __restrict__ x, unsigned short* __restrict__ xpc,
    float* __restrict__ pool_scr, unsigned* __restrict__ pmax_scr,
    float* __restrict__ s_avg, float* __restrict__ s_max)
{
    __shared__ unsigned tile[8192];   // [256px][32 words] bf16, swizzled
    __shared__ float scrS[8][64];
    __shared__ float scrM[8][64];
    const int t = threadIdx.x;
    const int b = blockIdx.x >> 8;
    const int pbase = (blockIdx.x & 255) << 8;
    const size_t xb = ((size_t)(b << 6)) * HW + pbase + t;
    const int s = (t & 7) << 2;       // swizzle term for this thread's row

    float psum = 0.f, pmax = -1e30f;
    #pragma unroll
    for (int cg = 0; cg < 4; ++cg) {  // 16 channels per batch, all loads independent
        float v[16];
        #pragma unroll
        for (int k = 0; k < 16; ++k)
            v[k] = x[xb + (size_t)((cg << 4) + k) * HW];
        #pragma unroll
        for (int k = 0; k < 16; ++k) { psum += v[k]; pmax = fmaxf(pmax, v[k]); }
        unsigned w[8];
        #pragma unroll
        for (int k = 0; k < 8; ++k) w[k] = f2bf(v[2 * k]) | (f2bf(v[2 * k + 1]) << 16);
        *(uint4*)&tile[(t << 5) + (((cg << 3)) ^ s)]     = make_uint4(w[0], w[1], w[2], w[3]);
        *(uint4*)&tile[(t << 5) + (((cg << 3) + 4) ^ s)] = make_uint4(w[4], w[5], w[6], w[7]);
    }
    s_avg[(size_t)b * HW + pbase + t] = psum * (1.f / 64.f);
    s_max[(size_t)b * HW + pbase + t] = pmax;
    __syncthreads();

    // transposed per-channel reduce: cp = word (2 channels), q = px octant
    {
        const int cp = t & 31, q = t >> 5;
        float s0 = 0.f, s1 = 0.f, m0 = -1e30f, m1 = -1e30f;
        #pragma unroll 8
        for (int i = 0; i < 32; ++i) {
            const int px = (q << 5) + i;
            const unsigned u = tile[(px << 5) + (cp ^ ((px & 7) << 2))];
            const float a0 = bf2f(u & 0xffffu), a1 = bf2f(u >> 16);
            s0 += a0; s1 += a1;
            m0 = fmaxf(m0, a0); m1 = fmaxf(m1, a1);
        }
        scrS[q][2 * cp] = s0; scrS[q][2 * cp + 1] = s1;
        scrM[q][2 * cp] = m0; scrM[q][2 * cp + 1] = m1;
    }
    // coalesced xpc dump: thread t writes 16B at flat offset k*4096 + t*16
    {
        unsigned short* xp = xpc + (((size_t)b * HW + pbase) << 6);
        #pragma unroll
        for (int k = 0; k < 8; ++k) {
            const int px = (k << 5) + (t >> 3);
            const int w = ((t & 7) << 2) ^ ((px & 7) << 2);
            const uint4 v = *(const uint4*)&tile[(px << 5) + w];
            *(uint4*)(xp + (k << 11) + (t << 3)) = v;
        }
    }
    __syncthreads();
    if (t < 64) {
        float ss = 0.f, mm = -1e30f;
        #pragma unroll
        for (int q = 0; q < 8; ++q) { ss += scrS[q][t]; mm = fmaxf(mm, scrM[q][t]); }
        const int copy = blockIdx.x & 7;
        atomicAdd(&pool_scr[(((b << 3) + copy) << 6) + t], ss);
        atomicMax(&pmax_scr[(((b << 3) + copy) << 6) + t], encf(mm));
    }
}

// ---------------------------------------------------------------------------
// P2: 7x7 spatial-attention conv + (row-0 blocks) channel-attention MLP.
__global__ __launch_bounds__(256) void k_sa_ca(
    const float* __restrict__ s_avg, const float* __restrict__ s_max,
    const float* __restrict__ w,
    const float* __restrict__ pool_scr, const unsigned* __restrict__ pmax_scr,
    const float* __restrict__ w1, const float* __restrict__ w2,
    float* __restrict__ sa, float* __restrict__ ca)
{
    const int t = threadIdx.x;
    const int b = blockIdx.x >> 8;
    const int pix = ((blockIdx.x & 255) << 8) | t;
    const int i = pix >> 8, j = pix & 255;
    float acc = 0.f;
    #pragma unroll
    for (int cin = 0; cin < 2; ++cin) {
        const float* src = (cin ? s_max : s_avg) + (size_t)b * HW;
        const float* wk = w + cin * 49;
        #pragma unroll
        for (int ki = 0; ki < 7; ++ki) {
            const int y = i + ki - 3;
            if ((unsigned)y < 256u) {
                #pragma unroll
                for (int kj = 0; kj < 7; ++kj) {
                    const int xx = j + kj - 3;
                    if ((unsigned)xx < 256u) acc += src[(y << 8) | xx] * wk[ki * 7 + kj];
                }
            }
        }
    }
    sa[(size_t)b * HW + pix] = sigm(acc);

    if ((blockIdx.x & 255) == 0) {   // block-uniform branch: also compute ca[b]
        __shared__ float av[CB], mv[CB], hh[8];
        if (t < CB) {
            float ss = 0.f; unsigned mm = 0u;
            #pragma unroll
            for (int r = 0; r < 8; ++r) {
                ss += pool_scr[(((b << 3) + r) << 6) + t];
                mm = max(mm, pmax_scr[(((b << 3) + r) << 6) + t]);
            }
            av[t] = ss * (1.f / (float)HW);
            mv[t] = decf(mm);
        }
        __syncthreads();
        if (t < 8) {
            const int h = t & 3;
            const float* v = (t < 4) ? av : mv;
            float ssum = 0;
            for (int c = 0; c < CB; ++c) ssum += w1[h * CB + c] * v[c];
            hh[t] = fmaxf(ssum, 0.f);
        }
        __syncthreads();
        if (t < CB) {
            float ssum = 0;
            #pragma unroll
            for (int h = 0; h < 4; ++h) ssum += w2[t * 4 + h] * (hh[h] + hh[4 + h]);
            ca[b * CB + t] = sigm(ssum);
        }
    }
}

// ---------------------------------------------------------------------------
// P4: MFMA main. 128-px tile/block, 4 waves. Reads xpc (bf16 [px][ch],
// contiguous), computes fuse in LDS, two MFMA GEMMs, writes d + GN partials.
__global__ __launch_bounds__(256, 3) void k_main(
    const unsigned short* __restrict__ xpc, const float* __restrict__ sa,
    const float* __restrict__ ca, const float* __restrict__ gw,
    const float* __restrict__ dw, const float* __restrict__ db,
    unsigned short* __restrict__ dbuf, float* __restrict__ gn_sum,
    float* __restrict__ gn_sq)
{
    __shared__ unsigned lds[12320];
    __shared__ float saL[128];
    __shared__ float caL[64];
    const int t = threadIdx.x;
    const int wv = t >> 6, l = t & 63, hi = l >> 4, lo = l & 15;
    const int b = blockIdx.x >> 9;
    const int pbase = (blockIdx.x & 511) << 7;

    // ---- stage weights: [outch][k] bf16, swizzled ----
    {
        const int orow = t >> 2, cq = (t & 3) << 4;
        const float* gsrc = gw + (orow << 6) + cq;
        const float* dsrc = dw + (orow << 6) + cq;
        unsigned ug[8], ud[8];
        #pragma unroll
        for (int j = 0; j < 8; ++j) {
            ug[j] = f2bf(gsrc[2 * j]) | (f2bf(gsrc[2 * j + 1]) << 16);
            ud[j] = f2bf(dsrc[2 * j]) | (f2bf(dsrc[2 * j + 1]) << 16);
        }
        const int wbase = (t & 3) << 3;
        *(uint4*)&lds[swz(orow, wbase)]            = make_uint4(ug[0], ug[1], ug[2], ug[3]);
        *(uint4*)&lds[swz(orow, wbase + 4)]        = make_uint4(ug[4], ug[5], ug[6], ug[7]);
        *(uint4*)&lds[2048 + swz(orow, wbase)]     = make_uint4(ud[0], ud[1], ud[2], ud[3]);
        *(uint4*)&lds[2048 + swz(orow, wbase + 4)] = make_uint4(ud[4], ud[5], ud[6], ud[7]);
    }
    // ---- stage sa/ca for the tile ----
    if (t < 128) saL[t] = sa[(size_t)b * HW + pbase + t];
    else if (t < 192) caL[t - 128] = ca[(b << 6) + (t - 128)];

    // ---- stage XT from xpc (contiguous 16B/lane) ----
    {
        const unsigned short* xp = xpc + (((size_t)b * HW + pbase) << 6);
        #pragma unroll
        for (int k = 0; k < 4; ++k) {
            const int idx = (k << 8) + t;      // 16B chunk id, flat
            const int px = idx >> 3;
            const int wg = (idx & 7) << 2;     // logical word group
            const uint4 v = *(const uint4*)(xp + (idx << 3));
            *(uint4*)&lds[8192 + (px << 5) + (wg ^ ((px & 7) << 2))] = v;
        }
    }
    __syncthreads();

    // ---- FT = XT * (sa + ca), bf16 in LDS ----
    {
        const int wb2 = (wv << 3) + (hi << 1);
        const int cbb = wb2 << 1;
        const float c0 = caL[cbb], c1 = caL[cbb + 1], c2 = caL[cbb + 2], c3 = caL[cbb + 3];
        #pragma unroll
        for (int n = 0; n < 8; ++n) {
            const int pxl = (n << 4) + lo;
            const float sv = saL[pxl];
            const uint2 xv = *(const uint2*)&lds[8192 + swz(pxl, wb2)];
            uint2 o;
            o.x = f2bf(bf2f(xv.x & 0xffffu) * (sv + c0)) | (f2bf(bf2f(xv.x >> 16) * (sv + c1)) << 16);
            o.y = f2bf(bf2f(xv.y & 0xffffu) * (sv + c2)) | (f2bf(bf2f(xv.y >> 16) * (sv + c3)) << 16);
            *(uint2*)&lds[4096 + swz(pxl, wb2)] = o;
        }
    }
    __syncthreads();

    // ---- GEMM1: guide logits = gate_w @ fuse ----
    f32x4 acc[8];
    #pragma unroll
    for (int n = 0; n < 8; ++n) acc[n] = (f32x4){0.f, 0.f, 0.f, 0.f};
    {
        const int arow = (wv << 4) + lo;
        const s16x8 a0 = __builtin_bit_cast(s16x8, *(const uint4*)&lds[swz(arow, hi << 2)]);
        const s16x8 a1 = __builtin_bit_cast(s16x8, *(const uint4*)&lds[swz(arow, (hi << 2) + 16)]);
        #pragma unroll
        for (int n = 0; n < 8; ++n) {
            const int brow = (n << 4) + lo;
            const s16x8 b0 = __builtin_bit_cast(s16x8, *(const uint4*)&lds[4096 + swz(brow, hi << 2)]);
            const s16x8 b1 = __builtin_bit_cast(s16x8, *(const uint4*)&lds[4096 + swz(brow, (hi << 2) + 16)]);
            acc[n] = __builtin_amdgcn_mfma_f32_16x16x32_bf16(a0, b0, acc[n], 0, 0, 0);
            acc[n] = __builtin_amdgcn_mfma_f32_16x16x32_bf16(a1, b1, acc[n], 0, 0, 0);
        }
    }
    __syncthreads();

    // ---- xg = x * sigmoid(logit) * mask, into FT ----
    {
        const bool row255 = (pbase >> 8) == 255;
        const bool halfblk = (pbase & 128) != 0;
        const int wb2 = (wv << 3) + (hi << 1);
        #pragma unroll
        for (int n = 0; n < 8; ++n) {
            const int pxl = (n << 4) + lo;
            const uint2 xv = *(const uint2*)&lds[8192 + swz(pxl, wb2)];
            const bool zero = row255 || (halfblk && pxl == 127);
            float xg0 = zero ? 0.f : bf2f(xv.x & 0xffffu) * sigm(acc[n][0]);
            float xg1 = zero ? 0.f : bf2f(xv.x >> 16)     * sigm(acc[n][1]);
            float xg2 = zero ? 0.f : bf2f(xv.y & 0xffffu) * sigm(acc[n][2]);
            float xg3 = zero ? 0.f : bf2f(xv.y >> 16)     * sigm(acc[n][3]);
            uint2 o;
            o.x = f2bf(xg0) | (f2bf(xg1) << 16);
            o.y = f2bf(xg2) | (f2bf(xg3) << 16);
            *(uint2*)&lds[4096 + swz(pxl, wb2)] = o;
        }
    }
    __syncthreads();

    // ---- GEMM2: d = dsc_w @ xg ----
    f32x4 acc2[8];
    #pragma unroll
    for (int n = 0; n < 8; ++n) acc2[n] = (f32x4){0.f, 0.f, 0.f, 0.f};
    {
        const int arow = (wv << 4) + lo;
        const s16x8 a0 = __builtin_bit_cast(s16x8, *(const uint4*)&lds[2048 + swz(arow, hi << 2)]);
        const s16x8 a1 = __builtin_bit_cast(s16x8, *(const uint4*)&lds[2048 + swz(arow, (hi << 2) + 16)]);
        #pragma unroll
        for (int n = 0; n < 8; ++n) {
            const int brow = (n << 4) + lo;
            const s16x8 b0 = __builtin_bit_cast(s16x8, *(const uint4*)&lds[4096 + swz(brow, hi << 2)]);
            const s16x8 b1 = __builtin_bit_cast(s16x8, *(const uint4*)&lds[4096 + swz(brow, (hi << 2) + 16)]);
            acc2[n] = __builtin_amdgcn_mfma_f32_16x16x32_bf16(a0, b0, acc2[n], 0, 0, 0);
            acc2[n] = __builtin_amdgcn_mfma_f32_16x16x32_bf16(a1, b1, acc2[n], 0, 0, 0);
        }
    }

    // ---- epilogue: bias + GN partials + direct channel-last d stores ----
    float gs = 0.f, gq = 0.f;
    {
        const float4 bv = *(const float4*)(db + (wv << 4) + (hi << 2));
        unsigned short* dp = dbuf + (((size_t)b * HW + pbase) << 6) + (wv << 4) + (hi << 2);
        #pragma unroll
        for (int n = 0; n < 8; ++n) {
            const int pxl = (n << 4) + lo;
            const float d0 = acc2[n][0] + bv.x, d1 = acc2[n][1] + bv.y;
            const float d2 = acc2[n][2] + bv.z, d3 = acc2[n][3] + bv.w;
            gs += d0 + d1 + d2 + d3;
            gq += d0 * d0 + d1 * d1 + d2 * d2 + d3 * d3;
            uint2 o;
            o.x = f2bf(d0) | (f2bf(d1) << 16);
            o.y = f2bf(d2) | (f2bf(d3) << 16);
            *(uint2*)(dp + ((size_t)pxl << 6)) = o;
        }
    }
    #pragma unroll
    for (int o = 1; o < 16; o <<= 1) { gs += __shfl_xor(gs, o); gq += __shfl_xor(gq, o); }
    float* smf = (float*)&lds[12288];
    if (lo == 0) { smf[(((wv << 2) + hi) << 1)] = gs; smf[(((wv << 2) + hi) << 1) + 1] = gq; }
    __syncthreads();
    if (t < 16) {
        atomicAdd(&gn_sum[(b << 4) + t], smf[2 * t]);
        atomicAdd(&gn_sq[(b << 4) + t],  smf[2 * t + 1]);
    }
}

// ---------------------------------------------------------------------------
// P5: y = relu(GN(d)) + x in-place on dbuf ([px][ch]); GN finalize inlined;
// BN stats into 8-way-spread scratch. grid = 2048 (256 px/block).
__global__ __launch_bounds__(256) void k_gnbn(
    const unsigned short* __restrict__ xpc, unsigned short* __restrict__ dy,
    const float* __restrict__ gn_sum, const float* __restrict__ gn_sq,
    const float* __restrict__ gamma, const float* __restrict__ beta,
    float* __restrict__ bn_scr)
{
    const int t = threadIdx.x;
    const size_t P0 = (size_t)blockIdx.x << 8;
    const int b = (int)(P0 >> 16);
    __shared__ float ga[CB], gb[CB];
    __shared__ float red[4][128];
    if (t < CB) {
        const int g = t >> 2;
        const float n4 = 4.f * (float)HW;
        const float mu = gn_sum[b * 16 + g] / n4;
        const float var = gn_sq[b * 16 + g] / n4 - mu * mu;
        const float a = rsqrtf(var + 1e-5f) * gamma[t];
        ga[t] = a; gb[t] = beta[t] - mu * a;
    }
    __syncthreads();
    const int o8 = (t & 7) << 3;
    float ar[8], br[8];
    #pragma unroll
    for (int k = 0; k < 8; ++k) { ar[k] = ga[o8 + k]; br[k] = gb[o8 + k]; }
    float as[8], aq[8];
    #pragma unroll
    for (int k = 0; k < 8; ++k) { as[k] = 0.f; aq[k] = 0.f; }
    for (int i = 0; i < 8; ++i) {
        const size_t P = P0 + (i << 5) + (t >> 3);
        const size_t idx = (P << 6) + o8;
        const uint4 dv = *(const uint4*)(dy + idx);
        const uint4 xv = *(const uint4*)(xpc + idx);
        const unsigned dw_[4] = {dv.x, dv.y, dv.z, dv.w};
        const unsigned xw_[4] = {xv.x, xv.y, xv.z, xv.w};
        uint4 o;
        unsigned ow_[4];
        #pragma unroll
        for (int p = 0; p < 4; ++p) {
            const int k0 = 2 * p;
            const float y0 = fmaxf(bf2f(dw_[p] & 0xffffu) * ar[k0] + br[k0], 0.f) + bf2f(xw_[p] & 0xffffu);
            const float y1 = fmaxf(bf2f(dw_[p] >> 16) * ar[k0 + 1] + br[k0 + 1], 0.f) + bf2f(xw_[p] >> 16);
            as[k0] += y0; aq[k0] += y0 * y0;
            as[k0 + 1] += y1; aq[k0 + 1] += y1 * y1;
            ow_[p] = f2bf(y0) | (f2bf(y1) << 16);
        }
        o.x = ow_[0]; o.y = ow_[1]; o.z = ow_[2]; o.w = ow_[3];
        *(uint4*)(dy + idx) = o;
    }
    #pragma unroll
    for (int k = 0; k < 8; ++k) {
        #pragma unroll
        for (int m = 8; m < 64; m <<= 1) {
            as[k] += __shfl_xor(as[k], m);
            aq[k] += __shfl_xor(aq[k], m);
        }
    }
    if ((t & 63) < 8) {
        const int o = t & 7, wvv = t >> 6;
        #pragma unroll
        for (int k = 0; k < 8; ++k) {
            red[wvv][o * 16 + k] = as[k];
            red[wvv][o * 16 + 8 + k] = aq[k];
        }
    }
    __syncthreads();
    if (t < 128) {
        const int o = t >> 4, st = (t >> 3) & 1, k = t & 7;
        const float v = red[0][t] + red[1][t] + red[2][t] + red[3][t];
        atomicAdd(&bn_scr[(blockIdx.x & 7) * 128 + st * 64 + o * 8 + k], v);
    }
}

// ---------------------------------------------------------------------------
// P6: out = ob + sum_c ow[c]*prelu(BN(y)); BN finalize inlined. grid = 2048.
__global__ __launch_bounds__(256) void k_out(
    const unsigned short* __restrict__ y, const float* __restrict__ bn_scr,
    const float* __restrict__ gamma, const float* __restrict__ beta,
    const float* __restrict__ pa, const float* __restrict__ ow,
    const float* __restrict__ ob, float* __restrict__ out)
{
    const int t = threadIdx.x;
    __shared__ float A[CB], Bs[CB], W[CB];
    if (t < CB) {
        float s = 0.f, q = 0.f;
        #pragma unroll
        for (int r = 0; r < 8; ++r) { s += bn_scr[r * 128 + t]; q += bn_scr[r * 128 + 64 + t]; }
        const float n = (float)NB * (float)HW;
        const float mu = s / n;
        const float var = q / n - mu * mu;
        const float a = rsqrtf(var + 1e-5f) * gamma[t];
        A[t] = a; Bs[t] = beta[t] - mu * a; W[t] = ow[t];
    }
    __syncthreads();
    const size_t P = ((size_t)blockIdx.x << 8) + t;
    const unsigned short* yp = y + (P << 6);
    const float alpha = pa[0];
    float acc = ob[0];
    #pragma unroll
    for (int q = 0; q < 8; ++q) {   // 8 x uint4 = 64 bf16 channels per pixel
        const uint4 v = *(const uint4*)(yp + (q << 3));
        const unsigned vw[4] = {v.x, v.y, v.z, v.w};
        #pragma unroll
        for (int p = 0; p < 4; ++p) {
            const int c = (q << 3) + 2 * p;
            float z0 = bf2f(vw[p] & 0xffffu) * A[c] + Bs[c];
            float z1 = bf2f(vw[p] >> 16) * A[c + 1] + Bs[c + 1];
            z0 = z0 >= 0.f ? z0 : alpha * z0;
            z1 = z1 >= 0.f ? z1 : alpha * z1;
            acc += W[c] * z0 + W[c + 1] * z1;
        }
    }
    out[P] = acc;
}

// ---------------------------------------------------------------------------
extern "C" void kernel_launch(void* const* d_in, const int* in_sizes, int n_in,
                              void* d_out, int out_size, void* d_ws, size_t ws_size,
                              hipStream_t stream)
{
    const float* x        = (const float*)d_in[0];
    const float* ca_w1    = (const float*)d_in[1];
    const float* ca_w2    = (const float*)d_in[2];
    const float* sa_w     = (const float*)d_in[3];
    const float* gate_w   = (const float*)d_in[4];
    // d_in[5..8]: offset branch — dead in forward math, skipped
    const float* dsc_w    = (const float*)d_in[9];
    const float* dsc_b    = (const float*)d_in[10];
    const float* gn_gamma = (const float*)d_in[11];
    const float* gn_beta  = (const float*)d_in[12];
    const float* bn_gamma = (const float*)d_in[13];
    const float* bn_beta  = (const float*)d_in[14];
    const float* prelu_a  = (const float*)d_in[15];
    const float* out_w    = (const float*)d_in[16];
    const float* out_b    = (const float*)d_in[17];
    float* out = (float*)d_out;

    char* ws = (char*)d_ws;
    size_t off = 0;
    auto alloc = [&](size_t bytes) -> char* {
        char* p = ws + off;
        off = (off + bytes + 255) & ~(size_t)255;
        return p;
    };
    unsigned short* dbuf = (unsigned short*)alloc((size_t)NB * HW * CB * 2);  // d -> y, [px][ch]
    unsigned short* xpc  = (unsigned short*)alloc((size_t)NB * HW * CB * 2);  // bf16 x, [px][ch]
    float* s_avg = (float*)alloc((size_t)NB * HW * 4);
    float* s_max = (float*)alloc((size_t)NB * HW * 4);
    float* sa    = (float*)alloc((size_t)NB * HW * 4);
    float* cav   = (float*)alloc(512 * 4);
    char* stats  = alloc(9472 * 4);   // contiguous zeroed accumulators
    float*    pool_scr = (float*)stats;                      // [NB][8][64]
    unsigned* pmax_scr = (unsigned*)(stats + 4096 * 4);      // [NB][8][64]
    float*    gn_sum   = (float*)(stats + 8192 * 4);         // [NB][16]
    float*    gn_sq    = (float*)(stats + 8320 * 4);         // [NB][16]
    float*    bn_scr   = (float*)(stats + 8448 * 4);         // [8][128]
    (void)in_sizes; (void)n_in; (void)out_size; (void)ws_size;

    hipMemsetAsync(stats, 0, 9472 * 4, stream);

    k_pre  <<<NB * 256, 256, 0, stream>>>(x, xpc, pool_scr, pmax_scr, s_avg, s_max);
    k_sa_ca<<<NB * 256, 256, 0, stream>>>(s_avg, s_max, sa_w, pool_scr, pmax_scr,
                                          ca_w1, ca_w2, sa, cav);
    k_main <<<NB * 512, 256, 0, stream>>>(xpc, sa, cav, gate_w, dsc_w, dsc_b,
                                          dbuf, gn_sum, gn_sq);
    k_gnbn <<<2048,     256, 0, stream>>>(xpc, dbuf, gn_sum, gn_sq, gn_gamma, gn_beta, bn_scr);
    k_out  <<<2048,     256, 0, stream>>>(dbuf, bn_scr, bn_gamma, bn_beta,
                                          prelu_a, out_w, out_b, out);
}

// Round 8
// 167.711 us; speedup vs baseline: 2.2395x; 1.0537x over previous
//
#include <hip/hip_runtime.h>

#define HW 65536
#define CB 64
#define NB 8

typedef __attribute__((ext_vector_type(4))) float f32x4;
typedef __attribute__((ext_vector_type(8))) short s16x8;

__device__ __forceinline__ float sigm(float v) { return 1.f / (1.f + __expf(-v)); }

__device__ __forceinline__ unsigned encf(float f) {
    unsigned u = __float_as_uint(f);
    return (u & 0x80000000u) ? ~u : (u | 0x80000000u);
}
__device__ __forceinline__ float decf(unsigned u) {
    return (u & 0x80000000u) ? __uint_as_float(u & 0x7fffffffu) : __uint_as_float(~u);
}
__device__ __forceinline__ unsigned f2bf(float f) {  // RNE, low 16 bits
    unsigned u = __float_as_uint(f);
    u += 0x7fffu + ((u >> 16) & 1u);
    return u >> 16;
}
__device__ __forceinline__ float bf2f(unsigned h) {
    return __uint_as_float(h << 16);
}
// swizzled word index for [row][32-word] bf16 tiles (row stride 128B)
__device__ __forceinline__ int swz(int row, int w) { return (row << 5) + (w ^ ((row & 7) << 2)); }

// ---------------------------------------------------------------------------
// P1 (k_pre): one pass over fp32 x ->
//   sm (per-px packed bf16 {channel-mean, channel-max}),
//   xpc (bf16 [px][64ch] copy via swizzled LDS transpose, coalesced dump),
//   per-channel pool sum/max partials (transposed LDS re-read, 8-way scratch).
// grid = NB*256 (256 px/block), block = 256 (thread == pixel).
__global__ __launch_bounds__(256) void k_pre(
    const float* __restrict__ x, unsigned short* __restrict__ xpc,
    float* __restrict__ pool_scr, unsigned* __restrict__ pmax_scr,
    unsigned* __restrict__ sm)
{
    __shared__ unsigned tile[8192];   // [256px][32 words] bf16, swizzled
    __shared__ float scrS[8][64];
    __shared__ float scrM[8][64];
    const int t = threadIdx.x;
    const int b = blockIdx.x >> 8;
    const int pbase = (blockIdx.x & 255) << 8;
    const size_t xb = ((size_t)(b << 6)) * HW + pbase + t;
    const int s = (t & 7) << 2;       // swizzle term for this thread's row

    float psum = 0.f, pmax = -1e30f;
    #pragma unroll
    for (int cg = 0; cg < 4; ++cg) {  // 16 channels per batch, all loads independent
        float v[16];
        #pragma unroll
        for (int k = 0; k < 16; ++k)
            v[k] = x[xb + (size_t)((cg << 4) + k) * HW];
        #pragma unroll
        for (int k = 0; k < 16; ++k) { psum += v[k]; pmax = fmaxf(pmax, v[k]); }
        unsigned w[8];
        #pragma unroll
        for (int k = 0; k < 8; ++k) w[k] = f2bf(v[2 * k]) | (f2bf(v[2 * k + 1]) << 16);
        *(uint4*)&tile[(t << 5) + (((cg << 3)) ^ s)]     = make_uint4(w[0], w[1], w[2], w[3]);
        *(uint4*)&tile[(t << 5) + (((cg << 3) + 4) ^ s)] = make_uint4(w[4], w[5], w[6], w[7]);
    }
    sm[(size_t)b * HW + pbase + t] = f2bf(psum * (1.f / 64.f)) | (f2bf(pmax) << 16);
    __syncthreads();

    // transposed per-channel reduce: cp = word (2 channels), q = px octant
    {
        const int cp = t & 31, q = t >> 5;
        float s0 = 0.f, s1 = 0.f, m0 = -1e30f, m1 = -1e30f;
        #pragma unroll 8
        for (int i = 0; i < 32; ++i) {
            const int px = (q << 5) + i;
            const unsigned u = tile[(px << 5) + (cp ^ ((px & 7) << 2))];
            const float a0 = bf2f(u & 0xffffu), a1 = bf2f(u >> 16);
            s0 += a0; s1 += a1;
            m0 = fmaxf(m0, a0); m1 = fmaxf(m1, a1);
        }
        scrS[q][2 * cp] = s0; scrS[q][2 * cp + 1] = s1;
        scrM[q][2 * cp] = m0; scrM[q][2 * cp + 1] = m1;
    }
    // coalesced xpc dump: thread t writes 16B at flat offset k*4096 + t*16
    {
        unsigned short* xp = xpc + (((size_t)b * HW + pbase) << 6);
        #pragma unroll
        for (int k = 0; k < 8; ++k) {
            const int px = (k << 5) + (t >> 3);
            const int w = ((t & 7) << 2) ^ ((px & 7) << 2);
            const uint4 v = *(const uint4*)&tile[(px << 5) + w];
            *(uint4*)(xp + (k << 11) + (t << 3)) = v;
        }
    }
    __syncthreads();
    if (t < 64) {
        float ss = 0.f, mm = -1e30f;
        #pragma unroll
        for (int q = 0; q < 8; ++q) { ss += scrS[q][t]; mm = fmaxf(mm, scrM[q][t]); }
        const int copy = blockIdx.x & 7;
        atomicAdd(&pool_scr[(((b << 3) + copy) << 6) + t], ss);
        atomicMax(&pmax_scr[(((b << 3) + copy) << 6) + t], encf(mm));
    }
}

// ---------------------------------------------------------------------------
// P2: 7x7 spatial-attention conv over packed bf16 {mean,max} maps (one uint
// load decodes both taps) + (row-0 blocks) channel-attention MLP. sa -> bf16.
__global__ __launch_bounds__(256) void k_sa_ca(
    const unsigned* __restrict__ sm, const float* __restrict__ w,
    const float* __restrict__ pool_scr, const unsigned* __restrict__ pmax_scr,
    const float* __restrict__ w1, const float* __restrict__ w2,
    unsigned short* __restrict__ sa, float* __restrict__ ca)
{
    const int t = threadIdx.x;
    const int b = blockIdx.x >> 8;
    const int pix = ((blockIdx.x & 255) << 8) | t;
    const int i = pix >> 8, j = pix & 255;
    const unsigned* src = sm + (size_t)b * HW;
    float acc = 0.f;
    #pragma unroll
    for (int ki = 0; ki < 7; ++ki) {
        const int y = i + ki - 3;
        if ((unsigned)y < 256u) {
            #pragma unroll
            for (int kj = 0; kj < 7; ++kj) {
                const int xx = j + kj - 3;
                if ((unsigned)xx < 256u) {
                    const unsigned u = src[(y << 8) | xx];
                    acc += bf2f(u & 0xffffu) * w[ki * 7 + kj] +
                           bf2f(u >> 16)     * w[49 + ki * 7 + kj];
                }
            }
        }
    }
    sa[(size_t)b * HW + pix] = (unsigned short)f2bf(sigm(acc));

    if ((blockIdx.x & 255) == 0) {   // block-uniform branch: also compute ca[b]
        __shared__ float av[CB], mv[CB], hh[8];
        if (t < CB) {
            float ss = 0.f; unsigned mm = 0u;
            #pragma unroll
            for (int r = 0; r < 8; ++r) {
                ss += pool_scr[(((b << 3) + r) << 6) + t];
                mm = max(mm, pmax_scr[(((b << 3) + r) << 6) + t]);
            }
            av[t] = ss * (1.f / (float)HW);
            mv[t] = decf(mm);
        }
        __syncthreads();
        if (t < 8) {
            const int h = t & 3;
            const float* v = (t < 4) ? av : mv;
            float ssum = 0;
            for (int c = 0; c < CB; ++c) ssum += w1[h * CB + c] * v[c];
            hh[t] = fmaxf(ssum, 0.f);
        }
        __syncthreads();
        if (t < CB) {
            float ssum = 0;
            #pragma unroll
            for (int h = 0; h < 4; ++h) ssum += w2[t * 4 + h] * (hh[h] + hh[4 + h]);
            ca[b * CB + t] = sigm(ssum);
        }
    }
}

// ---------------------------------------------------------------------------
// P4: MFMA main. 128-px tile/block, 4 waves. Reads xpc (bf16 [px][ch],
// contiguous), computes fuse in LDS, two MFMA GEMMs, writes d + GN partials.
__global__ __launch_bounds__(256, 3) void k_main(
    const unsigned short* __restrict__ xpc, const unsigned short* __restrict__ sa,
    const float* __restrict__ ca, const float* __restrict__ gw,
    const float* __restrict__ dw, const float* __restrict__ db,
    unsigned short* __restrict__ dbuf, float* __restrict__ gn_sum,
    float* __restrict__ gn_sq)
{
    __shared__ unsigned lds[12320];
    __shared__ float saL[128];
    __shared__ float caL[64];
    const int t = threadIdx.x;
    const int wv = t >> 6, l = t & 63, hi = l >> 4, lo = l & 15;
    const int b = blockIdx.x >> 9;
    const int pbase = (blockIdx.x & 511) << 7;

    // ---- stage weights: [outch][k] bf16, swizzled ----
    {
        const int orow = t >> 2, cq = (t & 3) << 4;
        const float* gsrc = gw + (orow << 6) + cq;
        const float* dsrc = dw + (orow << 6) + cq;
        unsigned ug[8], ud[8];
        #pragma unroll
        for (int j = 0; j < 8; ++j) {
            ug[j] = f2bf(gsrc[2 * j]) | (f2bf(gsrc[2 * j + 1]) << 16);
            ud[j] = f2bf(dsrc[2 * j]) | (f2bf(dsrc[2 * j + 1]) << 16);
        }
        const int wbase = (t & 3) << 3;
        *(uint4*)&lds[swz(orow, wbase)]            = make_uint4(ug[0], ug[1], ug[2], ug[3]);
        *(uint4*)&lds[swz(orow, wbase + 4)]        = make_uint4(ug[4], ug[5], ug[6], ug[7]);
        *(uint4*)&lds[2048 + swz(orow, wbase)]     = make_uint4(ud[0], ud[1], ud[2], ud[3]);
        *(uint4*)&lds[2048 + swz(orow, wbase + 4)] = make_uint4(ud[4], ud[5], ud[6], ud[7]);
    }
    // ---- stage sa/ca for the tile ----
    if (t < 128) saL[t] = bf2f(sa[(size_t)b * HW + pbase + t]);
    else if (t < 192) caL[t - 128] = ca[(b << 6) + (t - 128)];

    // ---- stage XT from xpc (contiguous 16B/lane) ----
    {
        const unsigned short* xp = xpc + (((size_t)b * HW + pbase) << 6);
        #pragma unroll
        for (int k = 0; k < 4; ++k) {
            const int idx = (k << 8) + t;      // 16B chunk id, flat
            const int px = idx >> 3;
            const int wg = (idx & 7) << 2;     // logical word group
            const uint4 v = *(const uint4*)(xp + (idx << 3));
            *(uint4*)&lds[8192 + (px << 5) + (wg ^ ((px & 7) << 2))] = v;
        }
    }
    __syncthreads();

    // ---- FT = XT * (sa + ca), bf16 in LDS ----
    {
        const int wb2 = (wv << 3) + (hi << 1);
        const int cbb = wb2 << 1;
        const float c0 = caL[cbb], c1 = caL[cbb + 1], c2 = caL[cbb + 2], c3 = caL[cbb + 3];
        #pragma unroll
        for (int n = 0; n < 8; ++n) {
            const int pxl = (n << 4) + lo;
            const float sv = saL[pxl];
            const uint2 xv = *(const uint2*)&lds[8192 + swz(pxl, wb2)];
            uint2 o;
            o.x = f2bf(bf2f(xv.x & 0xffffu) * (sv + c0)) | (f2bf(bf2f(xv.x >> 16) * (sv + c1)) << 16);
            o.y = f2bf(bf2f(xv.y & 0xffffu) * (sv + c2)) | (f2bf(bf2f(xv.y >> 16) * (sv + c3)) << 16);
            *(uint2*)&lds[4096 + swz(pxl, wb2)] = o;
        }
    }
    __syncthreads();

    // ---- GEMM1: guide logits = gate_w @ fuse ----
    f32x4 acc[8];
    #pragma unroll
    for (int n = 0; n < 8; ++n) acc[n] = (f32x4){0.f, 0.f, 0.f, 0.f};
    {
        const int arow = (wv << 4) + lo;
        const s16x8 a0 = __builtin_bit_cast(s16x8, *(const uint4*)&lds[swz(arow, hi << 2)]);
        const s16x8 a1 = __builtin_bit_cast(s16x8, *(const uint4*)&lds[swz(arow, (hi << 2) + 16)]);
        #pragma unroll
        for (int n = 0; n < 8; ++n) {
            const int brow = (n << 4) + lo;
            const s16x8 b0 = __builtin_bit_cast(s16x8, *(const uint4*)&lds[4096 + swz(brow, hi << 2)]);
            const s16x8 b1 = __builtin_bit_cast(s16x8, *(const uint4*)&lds[4096 + swz(brow, (hi << 2) + 16)]);
            acc[n] = __builtin_amdgcn_mfma_f32_16x16x32_bf16(a0, b0, acc[n], 0, 0, 0);
            acc[n] = __builtin_amdgcn_mfma_f32_16x16x32_bf16(a1, b1, acc[n], 0, 0, 0);
        }
    }
    __syncthreads();

    // ---- xg = x * sigmoid(logit) * mask, into FT ----
    {
        const bool row255 = (pbase >> 8) == 255;
        const bool halfblk = (pbase & 128) != 0;
        const int wb2 = (wv << 3) + (hi << 1);
        #pragma unroll
        for (int n = 0; n < 8; ++n) {
            const int pxl = (n << 4) + lo;
            const uint2 xv = *(const uint2*)&lds[8192 + swz(pxl, wb2)];
            const bool zero = row255 || (halfblk && pxl == 127);
            float xg0 = zero ? 0.f : bf2f(xv.x & 0xffffu) * sigm(acc[n][0]);
            float xg1 = zero ? 0.f : bf2f(xv.x >> 16)     * sigm(acc[n][1]);
            float xg2 = zero ? 0.f : bf2f(xv.y & 0xffffu) * sigm(acc[n][2]);
            float xg3 = zero ? 0.f : bf2f(xv.y >> 16)     * sigm(acc[n][3]);
            uint2 o;
            o.x = f2bf(xg0) | (f2bf(xg1) << 16);
            o.y = f2bf(xg2) | (f2bf(xg3) << 16);
            *(uint2*)&lds[4096 + swz(pxl, wb2)] = o;
        }
    }
    __syncthreads();

    // ---- GEMM2: d = dsc_w @ xg ----
    f32x4 acc2[8];
    #pragma unroll
    for (int n = 0; n < 8; ++n) acc2[n] = (f32x4){0.f, 0.f, 0.f, 0.f};
    {
        const int arow = (wv << 4) + lo;
        const s16x8 a0 = __builtin_bit_cast(s16x8, *(const uint4*)&lds[2048 + swz(arow, hi << 2)]);
        const s16x8 a1 = __builtin_bit_cast(s16x8, *(const uint4*)&lds[2048 + swz(arow, (hi << 2) + 16)]);
        #pragma unroll
        for (int n = 0; n < 8; ++n) {
            const int brow = (n << 4) + lo;
            const s16x8 b0 = __builtin_bit_cast(s16x8, *(const uint4*)&lds[4096 + swz(brow, hi << 2)]);
            const s16x8 b1 = __builtin_bit_cast(s16x8, *(const uint4*)&lds[4096 + swz(brow, (hi << 2) + 16)]);
            acc2[n] = __builtin_amdgcn_mfma_f32_16x16x32_bf16(a0, b0, acc2[n], 0, 0, 0);
            acc2[n] = __builtin_amdgcn_mfma_f32_16x16x32_bf16(a1, b1, acc2[n], 0, 0, 0);
        }
    }

    // ---- epilogue: bias + GN partials + direct channel-last d stores ----
    float gs = 0.f, gq = 0.f;
    {
        const float4 bv = *(const float4*)(db + (wv << 4) + (hi << 2));
        unsigned short* dp = dbuf + (((size_t)b * HW + pbase) << 6) + (wv << 4) + (hi << 2);
        #pragma unroll
        for (int n = 0; n < 8; ++n) {
            const int pxl = (n << 4) + lo;
            const float d0 = acc2[n][0] + bv.x, d1 = acc2[n][1] + bv.y;
            const float d2 = acc2[n][2] + bv.z, d3 = acc2[n][3] + bv.w;
            gs += d0 + d1 + d2 + d3;
            gq += d0 * d0 + d1 * d1 + d2 * d2 + d3 * d3;
            uint2 o;
            o.x = f2bf(d0) | (f2bf(d1) << 16);
            o.y = f2bf(d2) | (f2bf(d3) << 16);
            *(uint2*)(dp + ((size_t)pxl << 6)) = o;
        }
    }
    #pragma unroll
    for (int o = 1; o < 16; o <<= 1) { gs += __shfl_xor(gs, o); gq += __shfl_xor(gq, o); }
    float* smf = (float*)&lds[12288];
    if (lo == 0) { smf[(((wv << 2) + hi) << 1)] = gs; smf[(((wv << 2) + hi) << 1) + 1] = gq; }
    __syncthreads();
    if (t < 16) {
        atomicAdd(&gn_sum[(b << 4) + t], smf[2 * t]);
        atomicAdd(&gn_sq[(b << 4) + t],  smf[2 * t + 1]);
    }
}

// ---------------------------------------------------------------------------
// P5: y = relu(GN(d)) + x in-place on dbuf ([px][ch]); GN finalize inlined;
// BN stats into 8-way-spread scratch. grid = 2048 (256 px/block).
__global__ __launch_bounds__(256) void k_gnbn(
    const unsigned short* __restrict__ xpc, unsigned short* __restrict__ dy,
    const float* __restrict__ gn_sum, const float* __restrict__ gn_sq,
    const float* __restrict__ gamma, const float* __restrict__ beta,
    float* __restrict__ bn_scr)
{
    const int t = threadIdx.x;
    const size_t P0 = (size_t)blockIdx.x << 8;
    const int b = (int)(P0 >> 16);
    __shared__ float ga[CB], gb[CB];
    __shared__ float red[4][128];
    if (t < CB) {
        const int g = t >> 2;
        const float n4 = 4.f * (float)HW;
        const float mu = gn_sum[b * 16 + g] / n4;
        const float var = gn_sq[b * 16 + g] / n4 - mu * mu;
        const float a = rsqrtf(var + 1e-5f) * gamma[t];
        ga[t] = a; gb[t] = beta[t] - mu * a;
    }
    __syncthreads();
    const int o8 = (t & 7) << 3;
    float ar[8], br[8];
    #pragma unroll
    for (int k = 0; k < 8; ++k) { ar[k] = ga[o8 + k]; br[k] = gb[o8 + k]; }
    float as[8], aq[8];
    #pragma unroll
    for (int k = 0; k < 8; ++k) { as[k] = 0.f; aq[k] = 0.f; }
    for (int i = 0; i < 8; ++i) {
        const size_t P = P0 + (i << 5) + (t >> 3);
        const size_t idx = (P << 6) + o8;
        const uint4 dv = *(const uint4*)(dy + idx);
        const uint4 xv = *(const uint4*)(xpc + idx);
        const unsigned dw_[4] = {dv.x, dv.y, dv.z, dv.w};
        const unsigned xw_[4] = {xv.x, xv.y, xv.z, xv.w};
        uint4 o;
        unsigned ow_[4];
        #pragma unroll
        for (int p = 0; p < 4; ++p) {
            const int k0 = 2 * p;
            const float y0 = fmaxf(bf2f(dw_[p] & 0xffffu) * ar[k0] + br[k0], 0.f) + bf2f(xw_[p] & 0xffffu);
            const float y1 = fmaxf(bf2f(dw_[p] >> 16) * ar[k0 + 1] + br[k0 + 1], 0.f) + bf2f(xw_[p] >> 16);
            as[k0] += y0; aq[k0] += y0 * y0;
            as[k0 + 1] += y1; aq[k0 + 1] += y1 * y1;
            ow_[p] = f2bf(y0) | (f2bf(y1) << 16);
        }
        o.x = ow_[0]; o.y = ow_[1]; o.z = ow_[2]; o.w = ow_[3];
        *(uint4*)(dy + idx) = o;
    }
    #pragma unroll
    for (int k = 0; k < 8; ++k) {
        #pragma unroll
        for (int m = 8; m < 64; m <<= 1) {
            as[k] += __shfl_xor(as[k], m);
            aq[k] += __shfl_xor(aq[k], m);
        }
    }
    if ((t & 63) < 8) {
        const int o = t & 7, wvv = t >> 6;
        #pragma unroll
        for (int k = 0; k < 8; ++k) {
            red[wvv][o * 16 + k] = as[k];
            red[wvv][o * 16 + 8 + k] = aq[k];
        }
    }
    __syncthreads();
    if (t < 128) {
        const int o = t >> 4, st = (t >> 3) & 1, k = t & 7;
        const float v = red[0][t] + red[1][t] + red[2][t] + red[3][t];
        atomicAdd(&bn_scr[(blockIdx.x & 7) * 128 + st * 64 + o * 8 + k], v);
    }
}

// ---------------------------------------------------------------------------
// P6: out = ob + sum_c ow[c]*prelu(BN(y)); BN finalize inlined. grid = 2048.
__global__ __launch_bounds__(256) void k_out(
    const unsigned short* __restrict__ y, const float* __restrict__ bn_scr,
    const float* __restrict__ gamma, const float* __restrict__ beta,
    const float* __restrict__ pa, const float* __restrict__ ow,
    const float* __restrict__ ob, float* __restrict__ out)
{
    const int t = threadIdx.x;
    __shared__ float A[CB], Bs[CB], W[CB];
    if (t < CB) {
        float s = 0.f, q = 0.f;
        #pragma unroll
        for (int r = 0; r < 8; ++r) { s += bn_scr[r * 128 + t]; q += bn_scr[r * 128 + 64 + t]; }
        const float n = (float)NB * (float)HW;
        const float mu = s / n;
        const float var = q / n - mu * mu;
        const float a = rsqrtf(var + 1e-5f) * gamma[t];
        A[t] = a; Bs[t] = beta[t] - mu * a; W[t] = ow[t];
    }
    __syncthreads();
    const size_t P = ((size_t)blockIdx.x << 8) + t;
    const unsigned short* yp = y + (P << 6);
    const float alpha = pa[0];
    float acc = ob[0];
    #pragma unroll
    for (int q = 0; q < 8; ++q) {   // 8 x uint4 = 64 bf16 channels per pixel
        const uint4 v = *(const uint4*)(yp + (q << 3));
        const unsigned vw[4] = {v.x, v.y, v.z, v.w};
        #pragma unroll
        for (int p = 0; p < 4; ++p) {
            const int c = (q << 3) + 2 * p;
            float z0 = bf2f(vw[p] & 0xffffu) * A[c] + Bs[c];
            float z1 = bf2f(vw[p] >> 16) * A[c + 1] + Bs[c + 1];
            z0 = z0 >= 0.f ? z0 : alpha * z0;
            z1 = z1 >= 0.f ? z1 : alpha * z1;
            acc += W[c] * z0 + W[c + 1] * z1;
        }
    }
    out[P] = acc;
}

// ---------------------------------------------------------------------------
extern "C" void kernel_launch(void* const* d_in, const int* in_sizes, int n_in,
                              void* d_out, int out_size, void* d_ws, size_t ws_size,
                              hipStream_t stream)
{
    const float* x        = (const float*)d_in[0];
    const float* ca_w1    = (const float*)d_in[1];
    const float* ca_w2    = (const float*)d_in[2];
    const float* sa_w     = (const float*)d_in[3];
    const float* gate_w   = (const float*)d_in[4];
    // d_in[5..8]: offset branch — dead in forward math, skipped
    const float* dsc_w    = (const float*)d_in[9];
    const float* dsc_b    = (const float*)d_in[10];
    const float* gn_gamma = (const float*)d_in[11];
    const float* gn_beta  = (const float*)d_in[12];
    const float* bn_gamma = (const float*)d_in[13];
    const float* bn_beta  = (const float*)d_in[14];
    const float* prelu_a  = (const float*)d_in[15];
    const float* out_w    = (const float*)d_in[16];
    const float* out_b    = (const float*)d_in[17];
    float* out = (float*)d_out;

    char* ws = (char*)d_ws;
    size_t off = 0;
    auto alloc = [&](size_t bytes) -> char* {
        char* p = ws + off;
        off = (off + bytes + 255) & ~(size_t)255;
        return p;
    };
    unsigned short* dbuf = (unsigned short*)alloc((size_t)NB * HW * CB * 2);  // d -> y, [px][ch]
    unsigned short* xpc  = (unsigned short*)alloc((size_t)NB * HW * CB * 2);  // bf16 x, [px][ch]
    unsigned* smb        = (unsigned*)alloc((size_t)NB * HW * 4);             // packed bf16 {mean,max}
    unsigned short* sab  = (unsigned short*)alloc((size_t)NB * HW * 2);       // bf16 spatial attn
    float* cav   = (float*)alloc(512 * 4);
    char* stats  = alloc(9472 * 4);   // contiguous zeroed accumulators
    float*    pool_scr = (float*)stats;                      // [NB][8][64]
    unsigned* pmax_scr = (unsigned*)(stats + 4096 * 4);      // [NB][8][64]
    float*    gn_sum   = (float*)(stats + 8192 * 4);         // [NB][16]
    float*    gn_sq    = (float*)(stats + 8320 * 4);         // [NB][16]
    float*    bn_scr   = (float*)(stats + 8448 * 4);         // [8][128]
    (void)in_sizes; (void)n_in; (void)out_size; (void)ws_size;

    hipMemsetAsync(stats, 0, 9472 * 4, stream);

    k_pre  <<<NB * 256, 256, 0, stream>>>(x, xpc, pool_scr, pmax_scr, smb);
    k_sa_ca<<<NB * 256, 256, 0, stream>>>(smb, sa_w, pool_scr, pmax_scr,
                                          ca_w1, ca_w2, sab, cav);
    k_main <<<NB * 512, 256, 0, stream>>>(xpc, sab, cav, gate_w, dsc_w, dsc_b,
                                          dbuf, gn_sum, gn_sq);
    k_gnbn <<<2048,     256, 0, stream>>>(xpc, dbuf, gn_sum, gn_sq, gn_gamma, gn_beta, bn_scr);
    k_out  <<<2048,     256, 0, stream>>>(dbuf, bn_scr, bn_gamma, bn_beta,
                                          prelu_a, out_w, out_b, out);
}